// Round 9
// baseline (691.134 us; speedup 1.0000x reference)
//
#include <hip/hip_runtime.h>

#define NN 20000
#define EE 320000
#define KK 2000
#define KP 2048          // padded K-dim of E (zeros in 2000..2047)
#define SCALE 0.08838834764831845f
#define ZSPLIT 16        // attn_gemm partial slices
#define ACHUNKS 625      // 20000 / 32

typedef const float* cfp;
typedef __attribute__((ext_vector_type(8))) short sh8;
typedef __attribute__((ext_vector_type(4))) float f32x4;

static __device__ __forceinline__ float4 ld4(const float* p){ return *reinterpret_cast<const float4*>(p); }
static __device__ __forceinline__ void st4(float* p, float4 v){ *reinterpret_cast<float4*>(p) = v; }

static __device__ __forceinline__ unsigned short f2bf(float f){
    unsigned int u = __float_as_uint(f);
    u = (u + 0x7FFFu + ((u >> 16) & 1u)) >> 16;
    return (unsigned short)u;
}
static __device__ __forceinline__ float bf2f(unsigned short h){
    return __uint_as_float(((unsigned int)h) << 16);
}
static __device__ __forceinline__ sh8 lds8(const unsigned short* p){ return *reinterpret_cast<const sh8*>(p); }
static __device__ __forceinline__ sh8 ldnt8(const unsigned short* p){
    return __builtin_nontemporal_load(reinterpret_cast<const sh8*>(p));
}

// ---------------- CSR build ----------------
__global__ __launch_bounds__(256) void k_count(const int* dst, int* deg){
    int i = blockIdx.x*256 + threadIdx.x;
    if (i < EE) atomicAdd(&deg[dst[i]], 1);
}

__global__ __launch_bounds__(1024) void k_scan(const int* cnt, int* rows, float* dinv){
    __shared__ int part[1024];
    int t = threadIdx.x;
    int base = t*20;
    int s = 0;
    for (int i = 0; i < 20; ++i){ int idx = base+i; if (idx < NN) s += cnt[idx]; }
    part[t] = s; __syncthreads();
    for (int off = 1; off < 1024; off <<= 1){
        int v = (t >= off) ? part[t-off] : 0;
        __syncthreads();
        part[t] += v;
        __syncthreads();
    }
    int run = part[t] - s;   // exclusive
    for (int i = 0; i < 20; ++i){
        int idx = base+i;
        if (idx < NN){
            rows[idx] = run; run += cnt[idx];
            dinv[idx] = rsqrtf((float)cnt[idx] + 1.0f);
        }
    }
    if (t == 0) rows[NN] = EE;
}

__global__ __launch_bounds__(256) void k_fill(const int* src, const int* dst, const int* rows,
                                              int* cursor, int* col){
    int i = blockIdx.x*256 + threadIdx.x;
    if (i < EE){
        int d = dst[i];
        int pos = rows[d] + atomicAdd(&cursor[d], 1);
        col[pos] = src[i];
    }
}

// ---------------- weight transpose+convert ----------------
__global__ __launch_bounds__(256) void conv_wT(cfp w0, cfp w1, cfp w2, cfp w3, cfp w4, cfp w5, cfp w6,
                                               unsigned short* wts){
    const float* in;
    switch (blockIdx.z){
        case 0: in = w0; break; case 1: in = w1; break; case 2: in = w2; break;
        case 3: in = w3; break; case 4: in = w4; break; case 5: in = w5; break;
        default: in = w6; break;
    }
    unsigned short* out = wts + (size_t)blockIdx.z*16384;
    __shared__ float t[64][65];
    int r0 = blockIdx.x*64, c0 = blockIdx.y*64;
    int tid = threadIdx.x;
    for (int i = tid; i < 64*16; i += 256){
        int r = i >> 4, c4 = (i & 15) * 4;
        float4 v = ld4(in + (size_t)(r0+r)*128 + c0 + c4);
        t[r][c4+0]=v.x; t[r][c4+1]=v.y; t[r][c4+2]=v.z; t[r][c4+3]=v.w;
    }
    __syncthreads();
    for (int i = tid; i < 64*16; i += 256){
        int c = i >> 4, r4 = (i & 15) * 4;
        ushort4 o;
        o.x = f2bf(t[r4+0][c]); o.y = f2bf(t[r4+1][c]);
        o.z = f2bf(t[r4+2][c]); o.w = f2bf(t[r4+3][c]);
        *reinterpret_cast<ushort4*>(out + (size_t)(c0+c)*128 + r0 + r4) = o;
    }
}

// ---------------- fp32 GEMM (KK-sized only), optional bf16 dual-output ----------------
__global__ __launch_bounds__(512) void gemm128(const float* __restrict__ A, const float* __restrict__ Wm,
                                               float* __restrict__ C, int M,
                                               const float* bias, const float* resid, int relu,
                                               unsigned short* __restrict__ Cbf){
    __shared__ __align__(16) float Ws[128*132];
    __shared__ float As[64*129];
    int tid = threadIdx.x;
    int r0 = blockIdx.x*64;
    for (int i = tid; i < 128*32; i += 512){
        int r = i >> 5, c4 = (i & 31) * 4;
        float4 v = ld4(Wm + r*128 + c4);
        st4(&Ws[r*132 + c4], v);
    }
    for (int i = tid; i < 64*32; i += 512){
        int r = i >> 5, c4 = (i & 31) * 4;
        float4 v = (r0 + r < M) ? ld4(A + (size_t)(r0+r)*128 + c4) : make_float4(0,0,0,0);
        As[r*129 + c4+0] = v.x; As[r*129 + c4+1] = v.y;
        As[r*129 + c4+2] = v.z; As[r*129 + c4+3] = v.w;
    }
    __syncthreads();
    int a = tid >> 5;
    int b = tid & 31;
    float acc[4][4] = {};
    #pragma unroll 4
    for (int d = 0; d < 128; ++d){
        float4 w = ld4(&Ws[d*132 + 4*b]);
        float wv[4] = {w.x, w.y, w.z, w.w};
        float av[4];
        #pragma unroll
        for (int i = 0; i < 4; ++i) av[i] = As[(4*a+i)*129 + d];
        #pragma unroll
        for (int i = 0; i < 4; ++i)
            #pragma unroll
            for (int j = 0; j < 4; ++j)
                acc[i][j] += av[i]*wv[j];
    }
    int cc = 4*b;
    #pragma unroll
    for (int i = 0; i < 4; ++i){
        int r = r0 + 4*a + i;
        if (r < M){
            float v[4];
            #pragma unroll
            for (int j = 0; j < 4; ++j) v[j] = acc[i][j];
            if (bias){
                #pragma unroll
                for (int j = 0; j < 4; ++j) v[j] += bias[cc+j];
            }
            if (relu){
                #pragma unroll
                for (int j = 0; j < 4; ++j) v[j] = fmaxf(v[j], 0.f);
            }
            if (resid){
                float4 rv = ld4(resid + (size_t)r*128 + cc);
                v[0]+=rv.x; v[1]+=rv.y; v[2]+=rv.z; v[3]+=rv.w;
            }
            st4(C + (size_t)r*128 + cc, make_float4(v[0],v[1],v[2],v[3]));
            if (Cbf){
                ushort4 o;
                o.x = f2bf(v[0]); o.y = f2bf(v[1]); o.z = f2bf(v[2]); o.w = f2bf(v[3]);
                *reinterpret_cast<ushort4*>(Cbf + (size_t)r*128 + cc) = o;
            }
        }
    }
}

// ---------------- bf16 MFMA GEMM: 32m x 128n tiles (full-sector bf16 stores) ----------------
__global__ __launch_bounds__(256) void tgemm(const unsigned short* __restrict__ A, int M,
                                             const unsigned short* __restrict__ Wt,
                                             const float* __restrict__ rscale,
                                             unsigned short* __restrict__ C){
    int tid = threadIdx.x;
    int wave = tid >> 6, lane = tid & 63;
    int wm = wave >> 1, wn = wave & 1;
    int m_base = blockIdx.x*32 + wm*16;
    int l15 = lane & 15;
    int roff = (lane >> 4) * 8;
    const unsigned short* ap = A + (size_t)(m_base + l15)*128 + roff;
    const unsigned short* bp = Wt + (size_t)(wn*64 + l15)*128 + roff;
    f32x4 acc[4];
    #pragma unroll
    for (int j = 0; j < 4; ++j) acc[j] = (f32x4)0.f;
    #pragma unroll
    for (int r = 0; r < 128; r += 32){
        sh8 a = lds8(ap + r);
        #pragma unroll
        for (int j = 0; j < 4; ++j){
            sh8 b = lds8(bp + j*16*128 + r);
            acc[j] = __builtin_amdgcn_mfma_f32_16x16x32_bf16(a, b, acc[j], 0, 0, 0);
        }
    }
    int rq = (lane >> 4) * 4;
    #pragma unroll
    for (int ni = 0; ni < 4; ++ni){
        int gn = wn*64 + ni*16 + l15;
        #pragma unroll
        for (int reg = 0; reg < 4; ++reg){
            int gm = m_base + rq + reg;
            if (gm < M) C[(size_t)gm*128 + gn] = f2bf(acc[ni][reg] * (rscale ? rscale[gm] : 1.f));
        }
    }
}

// ---------------- GCN aggregation (bf16 in, fp32 accumulate), neighbor unroll 8 ----------------
__global__ __launch_bounds__(256) void gcn_agg_bf(const unsigned short* __restrict__ y, const float* __restrict__ dinv,
                                                  const int* __restrict__ rows, const int* __restrict__ col,
                                                  const float* __restrict__ bias, void* __restrict__ outv,
                                                  int relu, int out_fp32){
    int wid = (int)((blockIdx.x*256 + threadIdx.x) >> 6);
    int lane = threadIdx.x & 63;
    if (wid >= NN) return;
    int f = lane*2;
    ushort2 u = *reinterpret_cast<const ushort2*>(y + (size_t)wid*128 + f);
    float ax = bf2f(u.x), ay = bf2f(u.y);
    int s = rows[wid], e = rows[wid+1];
    int j = s;
    int e8 = s + ((e - s) & ~7);
    for (; j < e8; j += 8){
        ushort2 v[8];
        #pragma unroll
        for (int q = 0; q < 8; ++q){
            int c = col[j+q];
            v[q] = *reinterpret_cast<const ushort2*>(y + (size_t)c*128 + f);
        }
        #pragma unroll
        for (int q = 0; q < 8; ++q){ ax += bf2f(v[q].x); ay += bf2f(v[q].y); }
    }
    for (; j < e; ++j){
        int c0 = col[j];
        ushort2 v0 = *reinterpret_cast<const ushort2*>(y + (size_t)c0*128 + f);
        ax += bf2f(v0.x); ay += bf2f(v0.y);
    }
    float dn = dinv[wid];
    float ox = ax*dn + bias[f];
    float oy = ay*dn + bias[f+1];
    if (relu){ ox = fmaxf(ox, 0.f); oy = fmaxf(oy, 0.f); }
    if (out_fp32){
        *reinterpret_cast<float2*>((float*)outv + (size_t)wid*128 + f) = make_float2(ox, oy);
    } else {
        ushort2 o; o.x = f2bf(ox); o.y = f2bf(oy);
        *reinterpret_cast<ushort2*>((unsigned short*)outv + (size_t)wid*128 + f) = o;
    }
}

// ---------------- convert fp32 -> bf16 ----------------
__global__ __launch_bounds__(256) void conv_bf16(const float* __restrict__ in, unsigned short* __restrict__ out, int n4){
    int i = blockIdx.x*256 + threadIdx.x;
    if (i < n4){
        float4 v = ld4(in + (size_t)i*4);
        ushort4 o;
        o.x = f2bf(v.x); o.y = f2bf(v.y); o.z = f2bf(v.z); o.w = f2bf(v.w);
        *reinterpret_cast<ushort4*>(out + (size_t)i*4) = o;
    }
}

// ---------------- convert + transpose (+ optional per-source-row scale) ----------------
__global__ __launch_bounds__(256) void conv_bf16_T(const float* __restrict__ in, unsigned short* __restrict__ out,
                                                   int M, int ldout, const float* __restrict__ rscale){
    __shared__ float t[64][65];
    int r0 = blockIdx.x*64, c0 = blockIdx.y*64;
    int tid = threadIdx.x;
    for (int i = tid; i < 64*16; i += 256){
        int r = i >> 4, c4 = (i & 15) * 4;
        float4 v = (r0 + r < M) ? ld4(in + (size_t)(r0+r)*128 + c0 + c4) : make_float4(0,0,0,0);
        if (rscale && r0 + r < M){
            float sc = rscale[r0 + r];
            v.x *= sc; v.y *= sc; v.z *= sc; v.w *= sc;
        }
        t[r][c4+0]=v.x; t[r][c4+1]=v.y; t[r][c4+2]=v.z; t[r][c4+3]=v.w;
    }
    __syncthreads();
    for (int i = tid; i < 64*16; i += 256){
        int c = i >> 4, r4 = (i & 15) * 4;
        if (r0 + r4 < M){
            ushort4 o;
            o.x = f2bf(t[r4+0][c]); o.y = f2bf(t[r4+1][c]);
            o.z = f2bf(t[r4+2][c]); o.w = f2bf(t[r4+3][c]);
            *reinterpret_cast<ushort4*>(out + (size_t)(c0+c)*ldout + r0 + r4) = o;
        }
    }
}

// ---------------- z reduction: zinv[n] = 1/sum, zdinv[n] = zinv[n]*dinv[n] ----------------
__global__ __launch_bounds__(256) void k_rcp32(const float* __restrict__ zp, const float* __restrict__ dinv,
                                               float* __restrict__ zinv, float* __restrict__ zdinv){
    int n = blockIdx.x*256 + threadIdx.x;
    if (n < NN){
        float s = 0.f;
        #pragma unroll
        for (int y = 0; y < 16; ++y) s += zp[(size_t)y*NN + n];
        float zi = 1.f / s;
        zinv[n] = zi;
        zdinv[n] = zi * dinv[n];
    }
}

// ---------------- S-GEMM + exp + z-partials: 64n x 128k tiles, full-sector nt stores ----------------
__global__ __launch_bounds__(256) void s_gemm_exp(const unsigned short* __restrict__ Kb,
                                                  const unsigned short* __restrict__ Qb2,
                                                  unsigned short* __restrict__ E, float* __restrict__ zpart){
    __shared__ unsigned short Es[64*136];
    int tid = threadIdx.x;
    int wave = tid >> 6, lane = tid & 63;
    int wm = wave >> 1, wn = wave & 1;
    int n_blk = blockIdx.x*64, k_blk = blockIdx.y*128;
    int l15 = lane & 15;
    int roff = (lane >> 4) * 8;
    const unsigned short* ap0 = Kb + (size_t)(n_blk + wm*32 + l15)*128 + roff;
    const unsigned short* ap1 = ap0 + 16*128;
    const unsigned short* bp = Qb2 + (size_t)(k_blk + wn*64 + l15)*128 + roff;
    f32x4 acc[2][4];
    #pragma unroll
    for (int mi = 0; mi < 2; ++mi)
        #pragma unroll
        for (int j = 0; j < 4; ++j) acc[mi][j] = (f32x4)0.f;
    #pragma unroll
    for (int r = 0; r < 128; r += 32){
        sh8 a0 = lds8(ap0 + r);
        sh8 a1 = lds8(ap1 + r);
        #pragma unroll
        for (int j = 0; j < 4; ++j){
            sh8 b = lds8(bp + j*16*128 + r);
            acc[0][j] = __builtin_amdgcn_mfma_f32_16x16x32_bf16(a0, b, acc[0][j], 0, 0, 0);
            acc[1][j] = __builtin_amdgcn_mfma_f32_16x16x32_bf16(a1, b, acc[1][j], 0, 0, 0);
        }
    }
    int rq = (lane >> 4) * 4;
    #pragma unroll
    for (int mi = 0; mi < 2; ++mi){
        #pragma unroll
        for (int ni = 0; ni < 4; ++ni){
            f32x4 a = acc[mi][ni];
            int c_loc = wn*64 + ni*16 + l15;
            bool kv = (k_blk + c_loc) < KK;
            #pragma unroll
            for (int reg = 0; reg < 4; ++reg){
                int r_loc = wm*32 + mi*16 + rq + reg;
                float e = kv ? __expf(a[reg]*SCALE) : 0.f;
                Es[r_loc*136 + c_loc] = f2bf(e);
            }
        }
    }
    __syncthreads();
    if (tid < 64){
        int n = n_blk + tid;
        if (n < NN){
            float s = 0.f;
            #pragma unroll 8
            for (int j = 0; j < 128; ++j) s += bf2f(Es[tid*136 + j]);
            zpart[(size_t)blockIdx.y*NN + n] = s;
        }
    }
    // full 256B-per-row nontemporal store
    for (int i = tid; i < 1024; i += 256){
        int r = i >> 4, c8 = (i & 15) * 8;
        if (n_blk + r < NN){
            sh8 v = lds8(&Es[r*136 + c8]);
            union { sh8 s; unsigned long long q[2]; } u;
            u.s = v;
            unsigned long long* dst = reinterpret_cast<unsigned long long*>(E + (size_t)(n_blk + r)*KP + k_blk + c8);
            __builtin_nontemporal_store(u.q[0], dst);
            __builtin_nontemporal_store(u.q[1], dst + 1);
        }
    }
}

// ---------------- attn GEMM partials with next-chunk prefetch (nt E loads) ----------------
__global__ __launch_bounds__(256) void attn_gemm(const unsigned short* __restrict__ E,
                                                 const unsigned short* __restrict__ Vt,
                                                 float* __restrict__ part){
    __shared__ unsigned short As[64*36];
    int tid = threadIdx.x;
    int wave = tid >> 6, lane = tid & 63;
    int kk0 = blockIdx.x*64;
    int per = (ACHUNKS + ZSPLIT - 1) / ZSPLIT;
    int c0 = blockIdx.y*per;
    int c1 = min(ACHUNKS, c0 + per);
    int l15 = lane & 15;
    int q8 = (lane >> 4) * 8;
    int d0 = wave*32;
    int n_l = tid & 31;
    int k8 = (tid >> 5) * 8;
    f32x4 acc[4][2];
    #pragma unroll
    for (int g = 0; g < 4; ++g){ acc[g][0] = (f32x4)0.f; acc[g][1] = (f32x4)0.f; }
    const unsigned short* ebase = E + (size_t)n_l*KP + kk0 + k8;
    const unsigned short* vb0p = Vt + (size_t)(d0 + l15)*NN + q8;
    const unsigned short* vb1p = vb0p + (size_t)16*NN;
    sh8 etmp = ldnt8(ebase + (size_t)c0*32*KP);
    sh8 vb0 = lds8(vb0p + c0*32);
    sh8 vb1 = lds8(vb1p + c0*32);
    for (int ch = c0; ch < c1; ++ch){
        unsigned short tmp[8];
        *reinterpret_cast<sh8*>(tmp) = etmp;
        #pragma unroll
        for (int j = 0; j < 8; ++j) As[(k8 + j)*36 + n_l] = tmp[j];
        __syncthreads();
        sh8 etn = (sh8)0, vbn0 = (sh8)0, vbn1 = (sh8)0;
        if (ch + 1 < c1){
            etn  = ldnt8(ebase + (size_t)(ch+1)*32*KP);
            vbn0 = lds8(vb0p + (ch+1)*32);
            vbn1 = lds8(vb1p + (ch+1)*32);
        }
        #pragma unroll
        for (int g = 0; g < 4; ++g){
            const unsigned short* ap = &As[(g*16 + l15)*36 + q8];
            union { struct { ushort4 lo, hi; } u; sh8 v; } af;
            af.u.lo = *reinterpret_cast<const ushort4*>(ap);
            af.u.hi = *reinterpret_cast<const ushort4*>(ap + 4);
            acc[g][0] = __builtin_amdgcn_mfma_f32_16x16x32_bf16(af.v, vb0, acc[g][0], 0, 0, 0);
            acc[g][1] = __builtin_amdgcn_mfma_f32_16x16x32_bf16(af.v, vb1, acc[g][1], 0, 0, 0);
        }
        __syncthreads();
        etmp = etn; vb0 = vbn0; vb1 = vbn1;
    }
    float* pbase = part + (size_t)blockIdx.y*KK*128;
    int rq = (lane >> 4) * 4;
    #pragma unroll
    for (int g = 0; g < 4; ++g){
        #pragma unroll
        for (int ni = 0; ni < 2; ++ni){
            int d = d0 + ni*16 + l15;
            #pragma unroll
            for (int reg = 0; reg < 4; ++reg){
                int kk = kk0 + g*16 + rq + reg;
                if (kk < KK) pbase[(size_t)kk*128 + d] = acc[g][ni][reg];
            }
        }
    }
}

// ---------------- xout GEMM: K-split x2, db 64-wide batches, nt E loads ----------------
__global__ __launch_bounds__(256) void xout_gemm(const unsigned short* __restrict__ E,
                                                 const unsigned short* __restrict__ B,
                                                 float* __restrict__ xpart){
    int tid = threadIdx.x;
    int wave = tid >> 6, lane = tid & 63;
    int wm = wave >> 1, wn = wave & 1;
    int m_base = blockIdx.x*64 + wm*32;
    int n_base = blockIdx.y*64 + wn*32;
    int kz = blockIdx.z*1024;
    int l15 = lane & 15;
    int roff = (lane >> 4) * 8;
    const unsigned short* ap0 = E + (size_t)(m_base + l15)*KP + kz + roff;
    const unsigned short* ap1 = ap0 + (size_t)16*KP;
    const unsigned short* bp0 = B + (size_t)(n_base + l15)*KP + kz + roff;
    const unsigned short* bp1 = bp0 + (size_t)16*KP;
    f32x4 acc00 = (f32x4)0.f, acc01 = (f32x4)0.f, acc10 = (f32x4)0.f, acc11 = (f32x4)0.f;
    sh8 a0 = ldnt8(ap0),      a1 = ldnt8(ap1),      a2 = ldnt8(ap0 + 32), a3 = ldnt8(ap1 + 32);
    sh8 b0 = lds8(bp0),       b1 = lds8(bp1),       b2 = lds8(bp0 + 32),  b3 = lds8(bp1 + 32);
    for (int r = 0; r < 1024; r += 64){
        int rn = r + 64;
        sh8 na0 = (sh8)0, na1 = (sh8)0, na2 = (sh8)0, na3 = (sh8)0;
        sh8 nb0 = (sh8)0, nb1 = (sh8)0, nb2 = (sh8)0, nb3 = (sh8)0;
        if (rn < 1024){
            na0 = ldnt8(ap0 + rn);      na1 = ldnt8(ap1 + rn);
            na2 = ldnt8(ap0 + rn + 32); na3 = ldnt8(ap1 + rn + 32);
            nb0 = lds8(bp0 + rn);       nb1 = lds8(bp1 + rn);
            nb2 = lds8(bp0 + rn + 32);  nb3 = lds8(bp1 + rn + 32);
        }
        acc00 = __builtin_amdgcn_mfma_f32_16x16x32_bf16(a0, b0, acc00, 0, 0, 0);
        acc01 = __builtin_amdgcn_mfma_f32_16x16x32_bf16(a0, b1, acc01, 0, 0, 0);
        acc10 = __builtin_amdgcn_mfma_f32_16x16x32_bf16(a1, b0, acc10, 0, 0, 0);
        acc11 = __builtin_amdgcn_mfma_f32_16x16x32_bf16(a1, b1, acc11, 0, 0, 0);
        acc00 = __builtin_amdgcn_mfma_f32_16x16x32_bf16(a2, b2, acc00, 0, 0, 0);
        acc01 = __builtin_amdgcn_mfma_f32_16x16x32_bf16(a2, b3, acc01, 0, 0, 0);
        acc10 = __builtin_amdgcn_mfma_f32_16x16x32_bf16(a3, b2, acc10, 0, 0, 0);
        acc11 = __builtin_amdgcn_mfma_f32_16x16x32_bf16(a3, b3, acc11, 0, 0, 0);
        a0 = na0; a1 = na1; a2 = na2; a3 = na3;
        b0 = nb0; b1 = nb1; b2 = nb2; b3 = nb3;
    }
    float* pbase = xpart + (size_t)blockIdx.z*NN*128;
    int rq = (lane >> 4) * 4;
    f32x4 accs[2][2] = {{acc00, acc01},{acc10, acc11}};
    #pragma unroll
    for (int mi = 0; mi < 2; ++mi){
        #pragma unroll
        for (int ni = 0; ni < 2; ++ni){
            f32x4 a = accs[mi][ni];
            int gn = n_base + ni*16 + l15;
            #pragma unroll
            for (int reg = 0; reg < 4; ++reg){
                int gm = m_base + mi*16 + rq + reg;
                if (gm < NN) pbase[(size_t)gm*128 + gn] = a[reg];
            }
        }
    }
}

// ---------------- xout reduce: ybuf = bf16(zdinv[n] * (p0 + p1)) ----------------
__global__ __launch_bounds__(256) void xred(const float* __restrict__ xp, const float* __restrict__ zdinv,
                                            unsigned short* __restrict__ out){
    int i = blockIdx.x*256 + threadIdx.x;
    if (i < NN*32){
        int row = i >> 5;
        float4 p0 = ld4(xp + (size_t)i*4);
        float4 p1 = ld4(xp + (size_t)NN*128 + (size_t)i*4);
        float sc = zdinv[row];
        ushort4 o;
        o.x = f2bf((p0.x + p1.x)*sc);
        o.y = f2bf((p0.y + p1.y)*sc);
        o.z = f2bf((p0.z + p1.z)*sc);
        o.w = f2bf((p0.w + p1.w)*sc);
        *reinterpret_cast<ushort4*>(out + (size_t)i*4) = o;
    }
}

// ---------------- LayerNorm over D=128 (with partial-sum input) ----------------
__global__ __launch_bounds__(128) void ln_ker(const float* __restrict__ in, int nparts,
                                              const float* __restrict__ resid,
                                              const float* __restrict__ g, const float* __restrict__ be,
                                              float* __restrict__ out){
    __shared__ float rs[128], rq[128];
    int r = blockIdx.x, t = threadIdx.x;
    float v = 0.f;
    for (int p = 0; p < nparts; ++p) v += in[(size_t)p*KK*128 + r*128 + t];
    if (resid) v += resid[r*128 + t];
    rs[t] = v; rq[t] = v*v;
    __syncthreads();
    for (int off = 64; off > 0; off >>= 1){
        if (t < off){ rs[t] += rs[t+off]; rq[t] += rq[t+off]; }
        __syncthreads();
    }
    float mean = rs[0]*(1.f/128.f);
    float var = rq[0]*(1.f/128.f) - mean*mean;
    out[r*128 + t] = (v - mean)*rsqrtf(var + 1e-5f)*g[t] + be[t];
}

// ---------------- launcher ----------------
extern "C" void kernel_launch(void* const* d_in, const int* in_sizes, int n_in,
                              void* d_out, int out_size, void* d_ws, size_t ws_size,
                              hipStream_t stream){
    cfp x  = (cfp)d_in[0];
    const int* ei = (const int*)d_in[1];
    const int* esrc = ei;
    const int* edst = ei + EE;
    cfp W1=(cfp)d_in[3], b1=(cfp)d_in[4], W2=(cfp)d_in[5], b2=(cfp)d_in[6];
    cfp S =(cfp)d_in[7];
    cfp Wq=(cfp)d_in[8],  bq=(cfp)d_in[9],  Wk=(cfp)d_in[10], bk=(cfp)d_in[11];
    cfp Wv=(cfp)d_in[12], bv=(cfp)d_in[13], Wo=(cfp)d_in[14], bo=(cfp)d_in[15];
    cfp g0=(cfp)d_in[16], be0=(cfp)d_in[17], g1=(cfp)d_in[18], be1=(cfp)d_in[19];
    cfp Wl=(cfp)d_in[20], bl=(cfp)d_in[21], W3=(cfp)d_in[22], b3=(cfp)d_in[23];
    cfp W4=(cfp)d_in[24], b4=(cfp)d_in[25], W5=(cfp)d_in[26], b5=(cfp)d_in[27];

    char* wsb = (char*)d_ws;
    const size_t MB = 1048576;
    int*   deg    = (int*)  (wsb + 0);
    float* dinv   = (float*)(wsb + 81920);
    int*   rows   = (int*)  (wsb + 163840);
    int*   cursor = (int*)  (wsb + 245760);
    int*   col    = (int*)  (wsb + 327680);
    float* Qb     = (float*)(wsb + 2*MB);
    float* o1     = (float*)(wsb + 3*MB);    // also xl3 (fp32)
    float* o2     = (float*)(wsb + 4*MB);
    float* o3     = (float*)(wsb + 5*MB);
    float* xlb    = (float*)(wsb + 6*MB);
    float* zpart  = (float*)(wsb + 7*MB);                 // 16 x NN fp32
    float* zinv   = (float*)(wsb + 10*MB);
    float* zdinv  = (float*)(wsb + 10*MB + 131072);
    unsigned short* Wts  = (unsigned short*)(wsb + 10*MB + 262144);
    unsigned short* Qbf  = (unsigned short*)(wsb + 11*MB);
    unsigned short* xlt3 = (unsigned short*)(wsb + 11*MB + 524288);  // [128 x KP] bf16
    unsigned short* xbf = (unsigned short*)(wsb + 12*MB); // also h3
    unsigned short* h1  = (unsigned short*)(wsb + 17*MB); // also h4
    unsigned short* h2  = (unsigned short*)(wsb + 22*MB);
    unsigned short* ybuf= (unsigned short*)(wsb + 27*MB);
    unsigned short* Kbf = (unsigned short*)(wsb + 32*MB);
    unsigned short* Vtz = (unsigned short*)(wsb + 37*MB);
    // time-aliased region 42..62 MiB: NB3 (Vd fp32) -> part (16 MiB) -> xpart (19.6 MiB)
    float* NB3    = (float*)(wsb + 42*MB);
    float* part   = (float*)(wsb + 42*MB);
    float* xpart  = (float*)(wsb + 42*MB);
    unsigned short* E = (unsigned short*)(wsb + 62*MB);   // [NN x KP] bf16 = 78.1 MiB
    float* outp   = (float*)d_out;
    unsigned short* h3 = xbf;
    unsigned short* h4 = h1;

    (void)hipMemsetAsync(deg, 0, NN*sizeof(int), stream);
    (void)hipMemsetAsync(cursor, 0, NN*sizeof(int), stream);
    (void)hipMemsetAsync(xlt3, 0, 128*KP*sizeof(unsigned short), stream);  // pad cols must be finite

    // CSR build
    k_count<<<1250, 256, 0, stream>>>(edst, deg);
    k_scan<<<1, 1024, 0, stream>>>(deg, rows, dinv);
    k_fill<<<1250, 256, 0, stream>>>(esrc, edst, rows, cursor, col);

    // weights -> bf16 transposed; x -> bf16
    conv_wT<<<dim3(2,2,7), 256, 0, stream>>>(W1, W2, Wk, Wv, W3, W4, W5, Wts);
    conv_bf16<<<2500, 256, 0, stream>>>(x, xbf, NN*32);
    unsigned short* W1t = Wts;
    unsigned short* W2t = Wts + 16384;
    unsigned short* Wkt = Wts + 2*16384;
    unsigned short* Wvt = Wts + 3*16384;
    unsigned short* W4t = Wts + 5*16384;
    unsigned short* W5t = Wts + 6*16384;

    const int GN = 313;   // ceil(NN/64)
    const int GT = 625;   // NN/32
    const int GK = 32;    // ceil(KK/64) == KP/64

    // GCN1
    tgemm<<<GT, 256, 0, stream>>>(xbf, NN, W1t, dinv, ybuf);
    gcn_agg_bf<<<5000, 256, 0, stream>>>(ybuf, dinv, rows, col, b1, h1, 1, 0);
    // GCN2 -> h2
    tgemm<<<GT, 256, 0, stream>>>(h1, NN, W2t, dinv, ybuf);
    gcn_agg_bf<<<5000, 256, 0, stream>>>(ybuf, dinv, rows, col, b2, h2, 1, 0);
    // Kd -> Kbf (bf16)
    tgemm<<<GT, 256, 0, stream>>>(h2, NN, Wkt, dinv, ybuf);
    gcn_agg_bf<<<5000, 256, 0, stream>>>(ybuf, dinv, rows, col, bk, Kbf, 0, 0);
    // Q = S@Wq + bq (fp32) -> Qb + Qbf fused
    gemm128<<<GK, 512, 0, stream>>>(S, Wq, Qb, KK, bq, nullptr, 0, Qbf);
    // E = exp(SCALE * Kd Q^T), z partials
    s_gemm_exp<<<dim3(GN, 16), 256, 0, stream>>>(Kbf, Qbf, E, zpart);
    k_rcp32<<<79, 256, 0, stream>>>(zpart, dinv, zinv, zdinv);
    // Vd -> NB3 (fp32) -> Vtz (transposed bf16, pre-scaled by zinv[n])
    tgemm<<<GT, 256, 0, stream>>>(h2, NN, Wvt, dinv, ybuf);
    gcn_agg_bf<<<5000, 256, 0, stream>>>(ybuf, dinv, rows, col, bv, NB3, 0, 1);
    conv_bf16_T<<<dim3(GN, 2), 256, 0, stream>>>(NB3, Vtz, NN, NN, zinv);
    // attn partials (NB3 dead now; part aliases it)
    attn_gemm<<<dim3(GK, ZSPLIT), 256, 0, stream>>>(E, Vtz, part);
    // out = LN(sum(part) + Q)
    ln_ker<<<KK, 128, 0, stream>>>(part, ZSPLIT, Qb, g0, be0, o1);
    // o2 = o1 + relu(o1@Wo + bo)
    gemm128<<<GK, 512, 0, stream>>>(o1, Wo, o2, KK, bo, o1, 1, nullptr);
    ln_ker<<<KK, 128, 0, stream>>>(o2, 1, nullptr, g1, be1, o3);
    // xl = o3@Wl + bl ; xl3 = xl @ W3  (GCN3 weight folded into the seed side)
    gemm128<<<GK, 512, 0, stream>>>(o3, Wl, xlb, KK, bl, nullptr, 0, nullptr);
    gemm128<<<GK, 512, 0, stream>>>(xlb, W3, o1, KK, nullptr, nullptr, 0, nullptr);
    conv_bf16_T<<<dim3(GK, 2), 256, 0, stream>>>(o1, xlt3, KK, KP, nullptr);
    // ybuf[n] = bf16(zinv*dinv*(E[n] @ xl3))  == GCN3 pre-agg activations
    xout_gemm<<<dim3(GN, 2, 2), 256, 0, stream>>>(E, xlt3, xpart);
    xred<<<2500, 256, 0, stream>>>(xpart, zdinv, ybuf);
    // GCN3 aggregation
    gcn_agg_bf<<<5000, 256, 0, stream>>>(ybuf, dinv, rows, col, b3, h3, 1, 0);
    // GCN4
    tgemm<<<GT, 256, 0, stream>>>(h3, NN, W4t, dinv, ybuf);
    gcn_agg_bf<<<5000, 256, 0, stream>>>(ybuf, dinv, rows, col, b4, h4, 1, 0);
    // GCN5 -> d_out (fp32)
    tgemm<<<GT, 256, 0, stream>>>(h4, NN, W5t, dinv, ybuf);
    gcn_agg_bf<<<5000, 256, 0, stream>>>(ybuf, dinv, rows, col, b5, outp, 0, 1);
}

// Round 10
// 678.759 us; speedup vs baseline: 1.0182x; 1.0182x over previous
//
#include <hip/hip_runtime.h>

#define NN 20000
#define EE 320000
#define KK 2000
#define KP 2048          // padded K-dim of E (zeros in 2000..2047)
#define SCALE 0.08838834764831845f
#define ZSPLIT 16        // attn_gemm partial slices
#define ACHUNKS 625      // 20000 / 32

typedef const float* cfp;
typedef __attribute__((ext_vector_type(8))) short sh8;
typedef __attribute__((ext_vector_type(4))) float f32x4;

static __device__ __forceinline__ float4 ld4(const float* p){ return *reinterpret_cast<const float4*>(p); }
static __device__ __forceinline__ void st4(float* p, float4 v){ *reinterpret_cast<float4*>(p) = v; }

static __device__ __forceinline__ unsigned short f2bf(float f){
    unsigned int u = __float_as_uint(f);
    u = (u + 0x7FFFu + ((u >> 16) & 1u)) >> 16;
    return (unsigned short)u;
}
static __device__ __forceinline__ float bf2f(unsigned short h){
    return __uint_as_float(((unsigned int)h) << 16);
}
static __device__ __forceinline__ sh8 lds8(const unsigned short* p){ return *reinterpret_cast<const sh8*>(p); }
static __device__ __forceinline__ sh8 ldnt8(const unsigned short* p){
    return __builtin_nontemporal_load(reinterpret_cast<const sh8*>(p));
}

// ---------------- CSR build ----------------
__global__ __launch_bounds__(256) void k_count(const int* dst, int* deg){
    int i = blockIdx.x*256 + threadIdx.x;
    if (i < EE) atomicAdd(&deg[dst[i]], 1);
}

__global__ __launch_bounds__(1024) void k_scan(const int* cnt, int* rows, float* dinv){
    __shared__ int part[1024];
    int t = threadIdx.x;
    int base = t*20;
    int s = 0;
    for (int i = 0; i < 20; ++i){ int idx = base+i; if (idx < NN) s += cnt[idx]; }
    part[t] = s; __syncthreads();
    for (int off = 1; off < 1024; off <<= 1){
        int v = (t >= off) ? part[t-off] : 0;
        __syncthreads();
        part[t] += v;
        __syncthreads();
    }
    int run = part[t] - s;   // exclusive
    for (int i = 0; i < 20; ++i){
        int idx = base+i;
        if (idx < NN){
            rows[idx] = run; run += cnt[idx];
            dinv[idx] = rsqrtf((float)cnt[idx] + 1.0f);
        }
    }
    if (t == 0) rows[NN] = EE;
}

__global__ __launch_bounds__(256) void k_fill(const int* src, const int* dst, const int* rows,
                                              int* cursor, int* col){
    int i = blockIdx.x*256 + threadIdx.x;
    if (i < EE){
        int d = dst[i];
        int pos = rows[d] + atomicAdd(&cursor[d], 1);
        col[pos] = src[i];
    }
}

// ---------------- weight transpose+convert ----------------
__global__ __launch_bounds__(256) void conv_wT(cfp w0, cfp w1, cfp w2, cfp w3, cfp w4, cfp w5, cfp w6,
                                               unsigned short* wts){
    const float* in;
    switch (blockIdx.z){
        case 0: in = w0; break; case 1: in = w1; break; case 2: in = w2; break;
        case 3: in = w3; break; case 4: in = w4; break; case 5: in = w5; break;
        default: in = w6; break;
    }
    unsigned short* out = wts + (size_t)blockIdx.z*16384;
    __shared__ float t[64][65];
    int r0 = blockIdx.x*64, c0 = blockIdx.y*64;
    int tid = threadIdx.x;
    for (int i = tid; i < 64*16; i += 256){
        int r = i >> 4, c4 = (i & 15) * 4;
        float4 v = ld4(in + (size_t)(r0+r)*128 + c0 + c4);
        t[r][c4+0]=v.x; t[r][c4+1]=v.y; t[r][c4+2]=v.z; t[r][c4+3]=v.w;
    }
    __syncthreads();
    for (int i = tid; i < 64*16; i += 256){
        int c = i >> 4, r4 = (i & 15) * 4;
        ushort4 o;
        o.x = f2bf(t[r4+0][c]); o.y = f2bf(t[r4+1][c]);
        o.z = f2bf(t[r4+2][c]); o.w = f2bf(t[r4+3][c]);
        *reinterpret_cast<ushort4*>(out + (size_t)(c0+c)*128 + r0 + r4) = o;
    }
}

// ---------------- fp32 GEMM (KK-sized only), optional bf16 dual-output ----------------
__global__ __launch_bounds__(512) void gemm128(const float* __restrict__ A, const float* __restrict__ Wm,
                                               float* __restrict__ C, int M,
                                               const float* bias, const float* resid, int relu,
                                               unsigned short* __restrict__ Cbf){
    __shared__ __align__(16) float Ws[128*132];
    __shared__ float As[64*129];
    int tid = threadIdx.x;
    int r0 = blockIdx.x*64;
    for (int i = tid; i < 128*32; i += 512){
        int r = i >> 5, c4 = (i & 31) * 4;
        float4 v = ld4(Wm + r*128 + c4);
        st4(&Ws[r*132 + c4], v);
    }
    for (int i = tid; i < 64*32; i += 512){
        int r = i >> 5, c4 = (i & 31) * 4;
        float4 v = (r0 + r < M) ? ld4(A + (size_t)(r0+r)*128 + c4) : make_float4(0,0,0,0);
        As[r*129 + c4+0] = v.x; As[r*129 + c4+1] = v.y;
        As[r*129 + c4+2] = v.z; As[r*129 + c4+3] = v.w;
    }
    __syncthreads();
    int a = tid >> 5;
    int b = tid & 31;
    float acc[4][4] = {};
    #pragma unroll 4
    for (int d = 0; d < 128; ++d){
        float4 w = ld4(&Ws[d*132 + 4*b]);
        float wv[4] = {w.x, w.y, w.z, w.w};
        float av[4];
        #pragma unroll
        for (int i = 0; i < 4; ++i) av[i] = As[(4*a+i)*129 + d];
        #pragma unroll
        for (int i = 0; i < 4; ++i)
            #pragma unroll
            for (int j = 0; j < 4; ++j)
                acc[i][j] += av[i]*wv[j];
    }
    int cc = 4*b;
    #pragma unroll
    for (int i = 0; i < 4; ++i){
        int r = r0 + 4*a + i;
        if (r < M){
            float v[4];
            #pragma unroll
            for (int j = 0; j < 4; ++j) v[j] = acc[i][j];
            if (bias){
                #pragma unroll
                for (int j = 0; j < 4; ++j) v[j] += bias[cc+j];
            }
            if (relu){
                #pragma unroll
                for (int j = 0; j < 4; ++j) v[j] = fmaxf(v[j], 0.f);
            }
            if (resid){
                float4 rv = ld4(resid + (size_t)r*128 + cc);
                v[0]+=rv.x; v[1]+=rv.y; v[2]+=rv.z; v[3]+=rv.w;
            }
            st4(C + (size_t)r*128 + cc, make_float4(v[0],v[1],v[2],v[3]));
            if (Cbf){
                ushort4 o;
                o.x = f2bf(v[0]); o.y = f2bf(v[1]); o.z = f2bf(v[2]); o.w = f2bf(v[3]);
                *reinterpret_cast<ushort4*>(Cbf + (size_t)r*128 + cc) = o;
            }
        }
    }
}

// ---------------- bf16 MFMA GEMM: 32m x 128n tiles (full-sector bf16 stores) ----------------
__global__ __launch_bounds__(256) void tgemm(const unsigned short* __restrict__ A, int M,
                                             const unsigned short* __restrict__ Wt,
                                             const float* __restrict__ rscale,
                                             unsigned short* __restrict__ C){
    int tid = threadIdx.x;
    int wave = tid >> 6, lane = tid & 63;
    int wm = wave >> 1, wn = wave & 1;
    int m_base = blockIdx.x*32 + wm*16;
    int l15 = lane & 15;
    int roff = (lane >> 4) * 8;
    const unsigned short* ap = A + (size_t)(m_base + l15)*128 + roff;
    const unsigned short* bp = Wt + (size_t)(wn*64 + l15)*128 + roff;
    f32x4 acc[4];
    #pragma unroll
    for (int j = 0; j < 4; ++j) acc[j] = (f32x4)0.f;
    #pragma unroll
    for (int r = 0; r < 128; r += 32){
        sh8 a = lds8(ap + r);
        #pragma unroll
        for (int j = 0; j < 4; ++j){
            sh8 b = lds8(bp + j*16*128 + r);
            acc[j] = __builtin_amdgcn_mfma_f32_16x16x32_bf16(a, b, acc[j], 0, 0, 0);
        }
    }
    int rq = (lane >> 4) * 4;
    #pragma unroll
    for (int ni = 0; ni < 4; ++ni){
        int gn = wn*64 + ni*16 + l15;
        #pragma unroll
        for (int reg = 0; reg < 4; ++reg){
            int gm = m_base + rq + reg;
            if (gm < M) C[(size_t)gm*128 + gn] = f2bf(acc[ni][reg] * (rscale ? rscale[gm] : 1.f));
        }
    }
}

// ---------------- GCN aggregation (bf16 in, fp32 accumulate), neighbor unroll 8 ----------------
__global__ __launch_bounds__(256) void gcn_agg_bf(const unsigned short* __restrict__ y, const float* __restrict__ dinv,
                                                  const int* __restrict__ rows, const int* __restrict__ col,
                                                  const float* __restrict__ bias, void* __restrict__ outv,
                                                  int relu, int out_fp32){
    int wid = (int)((blockIdx.x*256 + threadIdx.x) >> 6);
    int lane = threadIdx.x & 63;
    if (wid >= NN) return;
    int f = lane*2;
    ushort2 u = *reinterpret_cast<const ushort2*>(y + (size_t)wid*128 + f);
    float ax = bf2f(u.x), ay = bf2f(u.y);
    int s = rows[wid], e = rows[wid+1];
    int j = s;
    int e8 = s + ((e - s) & ~7);
    for (; j < e8; j += 8){
        ushort2 v[8];
        #pragma unroll
        for (int q = 0; q < 8; ++q){
            int c = col[j+q];
            v[q] = *reinterpret_cast<const ushort2*>(y + (size_t)c*128 + f);
        }
        #pragma unroll
        for (int q = 0; q < 8; ++q){ ax += bf2f(v[q].x); ay += bf2f(v[q].y); }
    }
    for (; j < e; ++j){
        int c0 = col[j];
        ushort2 v0 = *reinterpret_cast<const ushort2*>(y + (size_t)c0*128 + f);
        ax += bf2f(v0.x); ay += bf2f(v0.y);
    }
    float dn = dinv[wid];
    float ox = ax*dn + bias[f];
    float oy = ay*dn + bias[f+1];
    if (relu){ ox = fmaxf(ox, 0.f); oy = fmaxf(oy, 0.f); }
    if (out_fp32){
        *reinterpret_cast<float2*>((float*)outv + (size_t)wid*128 + f) = make_float2(ox, oy);
    } else {
        ushort2 o; o.x = f2bf(ox); o.y = f2bf(oy);
        *reinterpret_cast<ushort2*>((unsigned short*)outv + (size_t)wid*128 + f) = o;
    }
}

// ---------------- convert fp32 -> bf16 ----------------
__global__ __launch_bounds__(256) void conv_bf16(const float* __restrict__ in, unsigned short* __restrict__ out, int n4){
    int i = blockIdx.x*256 + threadIdx.x;
    if (i < n4){
        float4 v = ld4(in + (size_t)i*4);
        ushort4 o;
        o.x = f2bf(v.x); o.y = f2bf(v.y); o.z = f2bf(v.z); o.w = f2bf(v.w);
        *reinterpret_cast<ushort4*>(out + (size_t)i*4) = o;
    }
}

// ---------------- convert + transpose (+ optional per-source-row scale) ----------------
__global__ __launch_bounds__(256) void conv_bf16_T(const float* __restrict__ in, unsigned short* __restrict__ out,
                                                   int M, int ldout, const float* __restrict__ rscale){
    __shared__ float t[64][65];
    int r0 = blockIdx.x*64, c0 = blockIdx.y*64;
    int tid = threadIdx.x;
    for (int i = tid; i < 64*16; i += 256){
        int r = i >> 4, c4 = (i & 15) * 4;
        float4 v = (r0 + r < M) ? ld4(in + (size_t)(r0+r)*128 + c0 + c4) : make_float4(0,0,0,0);
        if (rscale && r0 + r < M){
            float sc = rscale[r0 + r];
            v.x *= sc; v.y *= sc; v.z *= sc; v.w *= sc;
        }
        t[r][c4+0]=v.x; t[r][c4+1]=v.y; t[r][c4+2]=v.z; t[r][c4+3]=v.w;
    }
    __syncthreads();
    for (int i = tid; i < 64*16; i += 256){
        int c = i >> 4, r4 = (i & 15) * 4;
        if (r0 + r4 < M){
            ushort4 o;
            o.x = f2bf(t[r4+0][c]); o.y = f2bf(t[r4+1][c]);
            o.z = f2bf(t[r4+2][c]); o.w = f2bf(t[r4+3][c]);
            *reinterpret_cast<ushort4*>(out + (size_t)(c0+c)*ldout + r0 + r4) = o;
        }
    }
}

// ---------------- z reduction: zinv[n] = 1/sum, zdinv[n] = zinv[n]*dinv[n] ----------------
__global__ __launch_bounds__(256) void k_rcp32(const float* __restrict__ zp, const float* __restrict__ dinv,
                                               float* __restrict__ zinv, float* __restrict__ zdinv){
    int n = blockIdx.x*256 + threadIdx.x;
    if (n < NN){
        float s = 0.f;
        #pragma unroll
        for (int y = 0; y < 16; ++y) s += zp[(size_t)y*NN + n];
        float zi = 1.f / s;
        zinv[n] = zi;
        zdinv[n] = zi * dinv[n];
    }
}

// ---------------- S-GEMM + exp + z-partials: 64n x 128k tiles, full-sector nt stores ----------------
__global__ __launch_bounds__(256) void s_gemm_exp(const unsigned short* __restrict__ Kb,
                                                  const unsigned short* __restrict__ Qb2,
                                                  unsigned short* __restrict__ E, float* __restrict__ zpart){
    __shared__ unsigned short Es[64*136];
    int tid = threadIdx.x;
    int wave = tid >> 6, lane = tid & 63;
    int wm = wave >> 1, wn = wave & 1;
    int n_blk = blockIdx.x*64, k_blk = blockIdx.y*128;
    int l15 = lane & 15;
    int roff = (lane >> 4) * 8;
    const unsigned short* ap0 = Kb + (size_t)(n_blk + wm*32 + l15)*128 + roff;
    const unsigned short* ap1 = ap0 + 16*128;
    const unsigned short* bp = Qb2 + (size_t)(k_blk + wn*64 + l15)*128 + roff;
    f32x4 acc[2][4];
    #pragma unroll
    for (int mi = 0; mi < 2; ++mi)
        #pragma unroll
        for (int j = 0; j < 4; ++j) acc[mi][j] = (f32x4)0.f;
    #pragma unroll
    for (int r = 0; r < 128; r += 32){
        sh8 a0 = lds8(ap0 + r);
        sh8 a1 = lds8(ap1 + r);
        #pragma unroll
        for (int j = 0; j < 4; ++j){
            sh8 b = lds8(bp + j*16*128 + r);
            acc[0][j] = __builtin_amdgcn_mfma_f32_16x16x32_bf16(a0, b, acc[0][j], 0, 0, 0);
            acc[1][j] = __builtin_amdgcn_mfma_f32_16x16x32_bf16(a1, b, acc[1][j], 0, 0, 0);
        }
    }
    int rq = (lane >> 4) * 4;
    #pragma unroll
    for (int mi = 0; mi < 2; ++mi){
        #pragma unroll
        for (int ni = 0; ni < 4; ++ni){
            f32x4 a = acc[mi][ni];
            int c_loc = wn*64 + ni*16 + l15;
            bool kv = (k_blk + c_loc) < KK;
            #pragma unroll
            for (int reg = 0; reg < 4; ++reg){
                int r_loc = wm*32 + mi*16 + rq + reg;
                float e = kv ? __expf(a[reg]*SCALE) : 0.f;
                Es[r_loc*136 + c_loc] = f2bf(e);
            }
        }
    }
    __syncthreads();
    if (tid < 64){
        int n = n_blk + tid;
        if (n < NN){
            float s = 0.f;
            #pragma unroll 8
            for (int j = 0; j < 128; ++j) s += bf2f(Es[tid*136 + j]);
            zpart[(size_t)blockIdx.y*NN + n] = s;
        }
    }
    // full 256B-per-row nontemporal store
    for (int i = tid; i < 1024; i += 256){
        int r = i >> 4, c8 = (i & 15) * 8;
        if (n_blk + r < NN){
            sh8 v = lds8(&Es[r*136 + c8]);
            union { sh8 s; unsigned long long q[2]; } u;
            u.s = v;
            unsigned long long* dst = reinterpret_cast<unsigned long long*>(E + (size_t)(n_blk + r)*KP + k_blk + c8);
            __builtin_nontemporal_store(u.q[0], dst);
            __builtin_nontemporal_store(u.q[1], dst + 1);
        }
    }
}

// ---------------- attn GEMM partials with next-chunk prefetch (nt E loads; exactly-once reads) ----------------
__global__ __launch_bounds__(256) void attn_gemm(const unsigned short* __restrict__ E,
                                                 const unsigned short* __restrict__ Vt,
                                                 float* __restrict__ part){
    __shared__ unsigned short As[64*36];
    int tid = threadIdx.x;
    int wave = tid >> 6, lane = tid & 63;
    int kk0 = blockIdx.x*64;
    int per = (ACHUNKS + ZSPLIT - 1) / ZSPLIT;
    int c0 = blockIdx.y*per;
    int c1 = min(ACHUNKS, c0 + per);
    int l15 = lane & 15;
    int q8 = (lane >> 4) * 8;
    int d0 = wave*32;
    int n_l = tid & 31;
    int k8 = (tid >> 5) * 8;
    f32x4 acc[4][2];
    #pragma unroll
    for (int g = 0; g < 4; ++g){ acc[g][0] = (f32x4)0.f; acc[g][1] = (f32x4)0.f; }
    const unsigned short* ebase = E + (size_t)n_l*KP + kk0 + k8;
    const unsigned short* vb0p = Vt + (size_t)(d0 + l15)*NN + q8;
    const unsigned short* vb1p = vb0p + (size_t)16*NN;
    sh8 etmp = ldnt8(ebase + (size_t)c0*32*KP);
    sh8 vb0 = lds8(vb0p + c0*32);
    sh8 vb1 = lds8(vb1p + c0*32);
    for (int ch = c0; ch < c1; ++ch){
        unsigned short tmp[8];
        *reinterpret_cast<sh8*>(tmp) = etmp;
        #pragma unroll
        for (int j = 0; j < 8; ++j) As[(k8 + j)*36 + n_l] = tmp[j];
        __syncthreads();
        sh8 etn = (sh8)0, vbn0 = (sh8)0, vbn1 = (sh8)0;
        if (ch + 1 < c1){
            etn  = ldnt8(ebase + (size_t)(ch+1)*32*KP);
            vbn0 = lds8(vb0p + (ch+1)*32);
            vbn1 = lds8(vb1p + (ch+1)*32);
        }
        #pragma unroll
        for (int g = 0; g < 4; ++g){
            const unsigned short* ap = &As[(g*16 + l15)*36 + q8];
            union { struct { ushort4 lo, hi; } u; sh8 v; } af;
            af.u.lo = *reinterpret_cast<const ushort4*>(ap);
            af.u.hi = *reinterpret_cast<const ushort4*>(ap + 4);
            acc[g][0] = __builtin_amdgcn_mfma_f32_16x16x32_bf16(af.v, vb0, acc[g][0], 0, 0, 0);
            acc[g][1] = __builtin_amdgcn_mfma_f32_16x16x32_bf16(af.v, vb1, acc[g][1], 0, 0, 0);
        }
        __syncthreads();
        etmp = etn; vb0 = vbn0; vb1 = vbn1;
    }
    float* pbase = part + (size_t)blockIdx.y*KK*128;
    int rq = (lane >> 4) * 4;
    #pragma unroll
    for (int g = 0; g < 4; ++g){
        #pragma unroll
        for (int ni = 0; ni < 2; ++ni){
            int d = d0 + ni*16 + l15;
            #pragma unroll
            for (int reg = 0; reg < 4; ++reg){
                int kk = kk0 + g*16 + rq + reg;
                if (kk < KK) pbase[(size_t)kk*128 + d] = acc[g][ni][reg];
            }
        }
    }
}

// ---------------- xout GEMM: 32m x 128n tiles, K-split x2, cached E loads, prefetch depth 1 ----------------
__global__ __launch_bounds__(256) void xout_gemm(const unsigned short* __restrict__ E,
                                                 const unsigned short* __restrict__ B,
                                                 float* __restrict__ xpart){
    int tid = threadIdx.x;
    int wave = tid >> 6, lane = tid & 63;
    int wm = wave >> 1, wn = wave & 1;
    int m_base = blockIdx.x*32 + wm*16;
    int kz = blockIdx.y*1024;
    int l15 = lane & 15;
    int roff = (lane >> 4) * 8;
    const unsigned short* ap = E + (size_t)(m_base + l15)*KP + kz + roff;
    const unsigned short* bp = B + (size_t)(wn*64 + l15)*KP + kz + roff;
    f32x4 acc[4];
    #pragma unroll
    for (int j = 0; j < 4; ++j) acc[j] = (f32x4)0.f;
    sh8 a  = lds8(ap);
    sh8 b0 = lds8(bp), b1 = lds8(bp + 16*KP), b2 = lds8(bp + 32*KP), b3 = lds8(bp + 48*KP);
    for (int r = 0; r < 1024; r += 32){
        int rn = r + 32;
        sh8 na = (sh8)0, nb0 = (sh8)0, nb1 = (sh8)0, nb2 = (sh8)0, nb3 = (sh8)0;
        if (rn < 1024){
            na  = lds8(ap + rn);
            nb0 = lds8(bp + rn);
            nb1 = lds8(bp + 16*KP + rn);
            nb2 = lds8(bp + 32*KP + rn);
            nb3 = lds8(bp + 48*KP + rn);
        }
        acc[0] = __builtin_amdgcn_mfma_f32_16x16x32_bf16(a, b0, acc[0], 0, 0, 0);
        acc[1] = __builtin_amdgcn_mfma_f32_16x16x32_bf16(a, b1, acc[1], 0, 0, 0);
        acc[2] = __builtin_amdgcn_mfma_f32_16x16x32_bf16(a, b2, acc[2], 0, 0, 0);
        acc[3] = __builtin_amdgcn_mfma_f32_16x16x32_bf16(a, b3, acc[3], 0, 0, 0);
        a = na; b0 = nb0; b1 = nb1; b2 = nb2; b3 = nb3;
    }
    float* pbase = xpart + (size_t)blockIdx.y*NN*128;
    int rq = (lane >> 4) * 4;
    #pragma unroll
    for (int ni = 0; ni < 4; ++ni){
        int gn = wn*64 + ni*16 + l15;
        #pragma unroll
        for (int reg = 0; reg < 4; ++reg){
            int gm = m_base + rq + reg;
            if (gm < NN) pbase[(size_t)gm*128 + gn] = acc[ni][reg];
        }
    }
}

// ---------------- xout reduce: ybuf = bf16(zdinv[n] * (p0 + p1)) ----------------
__global__ __launch_bounds__(256) void xred(const float* __restrict__ xp, const float* __restrict__ zdinv,
                                            unsigned short* __restrict__ out){
    int i = blockIdx.x*256 + threadIdx.x;
    if (i < NN*32){
        int row = i >> 5;
        float4 p0 = ld4(xp + (size_t)i*4);
        float4 p1 = ld4(xp + (size_t)NN*128 + (size_t)i*4);
        float sc = zdinv[row];
        ushort4 o;
        o.x = f2bf((p0.x + p1.x)*sc);
        o.y = f2bf((p0.y + p1.y)*sc);
        o.z = f2bf((p0.z + p1.z)*sc);
        o.w = f2bf((p0.w + p1.w)*sc);
        *reinterpret_cast<ushort4*>(out + (size_t)i*4) = o;
    }
}

// ---------------- LayerNorm over D=128 (with partial-sum input) ----------------
__global__ __launch_bounds__(128) void ln_ker(const float* __restrict__ in, int nparts,
                                              const float* __restrict__ resid,
                                              const float* __restrict__ g, const float* __restrict__ be,
                                              float* __restrict__ out){
    __shared__ float rs[128], rq[128];
    int r = blockIdx.x, t = threadIdx.x;
    float v = 0.f;
    for (int p = 0; p < nparts; ++p) v += in[(size_t)p*KK*128 + r*128 + t];
    if (resid) v += resid[r*128 + t];
    rs[t] = v; rq[t] = v*v;
    __syncthreads();
    for (int off = 64; off > 0; off >>= 1){
        if (t < off){ rs[t] += rs[t+off]; rq[t] += rq[t+off]; }
        __syncthreads();
    }
    float mean = rs[0]*(1.f/128.f);
    float var = rq[0]*(1.f/128.f) - mean*mean;
    out[r*128 + t] = (v - mean)*rsqrtf(var + 1e-5f)*g[t] + be[t];
}

// ---------------- launcher ----------------
extern "C" void kernel_launch(void* const* d_in, const int* in_sizes, int n_in,
                              void* d_out, int out_size, void* d_ws, size_t ws_size,
                              hipStream_t stream){
    cfp x  = (cfp)d_in[0];
    const int* ei = (const int*)d_in[1];
    const int* esrc = ei;
    const int* edst = ei + EE;
    cfp W1=(cfp)d_in[3], b1=(cfp)d_in[4], W2=(cfp)d_in[5], b2=(cfp)d_in[6];
    cfp S =(cfp)d_in[7];
    cfp Wq=(cfp)d_in[8],  bq=(cfp)d_in[9],  Wk=(cfp)d_in[10], bk=(cfp)d_in[11];
    cfp Wv=(cfp)d_in[12], bv=(cfp)d_in[13], Wo=(cfp)d_in[14], bo=(cfp)d_in[15];
    cfp g0=(cfp)d_in[16], be0=(cfp)d_in[17], g1=(cfp)d_in[18], be1=(cfp)d_in[19];
    cfp Wl=(cfp)d_in[20], bl=(cfp)d_in[21], W3=(cfp)d_in[22], b3=(cfp)d_in[23];
    cfp W4=(cfp)d_in[24], b4=(cfp)d_in[25], W5=(cfp)d_in[26], b5=(cfp)d_in[27];

    char* wsb = (char*)d_ws;
    const size_t MB = 1048576;
    int*   deg    = (int*)  (wsb + 0);
    float* dinv   = (float*)(wsb + 81920);
    int*   rows   = (int*)  (wsb + 163840);
    int*   cursor = (int*)  (wsb + 245760);
    int*   col    = (int*)  (wsb + 327680);
    float* Qb     = (float*)(wsb + 2*MB);
    float* o1     = (float*)(wsb + 3*MB);    // also xl3 (fp32)
    float* o2     = (float*)(wsb + 4*MB);
    float* o3     = (float*)(wsb + 5*MB);
    float* xlb    = (float*)(wsb + 6*MB);
    float* zpart  = (float*)(wsb + 7*MB);                 // 16 x NN fp32
    float* zinv   = (float*)(wsb + 10*MB);
    float* zdinv  = (float*)(wsb + 10*MB + 131072);
    unsigned short* Wts  = (unsigned short*)(wsb + 10*MB + 262144);
    unsigned short* Qbf  = (unsigned short*)(wsb + 11*MB);
    unsigned short* xlt3 = (unsigned short*)(wsb + 11*MB + 524288);  // [128 x KP] bf16
    unsigned short* xbf = (unsigned short*)(wsb + 12*MB); // also h3
    unsigned short* h1  = (unsigned short*)(wsb + 17*MB); // also h4
    unsigned short* h2  = (unsigned short*)(wsb + 22*MB);
    unsigned short* ybuf= (unsigned short*)(wsb + 27*MB);
    unsigned short* Kbf = (unsigned short*)(wsb + 32*MB);
    unsigned short* Vtz = (unsigned short*)(wsb + 37*MB);
    // time-aliased region 42..62 MiB: NB3 (Vd fp32) -> part (16 MiB) -> xpart (19.6 MiB)
    float* NB3    = (float*)(wsb + 42*MB);
    float* part   = (float*)(wsb + 42*MB);
    float* xpart  = (float*)(wsb + 42*MB);
    unsigned short* E = (unsigned short*)(wsb + 62*MB);   // [NN x KP] bf16 = 78.1 MiB
    float* outp   = (float*)d_out;
    unsigned short* h3 = xbf;
    unsigned short* h4 = h1;

    (void)hipMemsetAsync(deg, 0, NN*sizeof(int), stream);
    (void)hipMemsetAsync(cursor, 0, NN*sizeof(int), stream);
    (void)hipMemsetAsync(xlt3, 0, 128*KP*sizeof(unsigned short), stream);  // pad cols must be finite

    // CSR build
    k_count<<<1250, 256, 0, stream>>>(edst, deg);
    k_scan<<<1, 1024, 0, stream>>>(deg, rows, dinv);
    k_fill<<<1250, 256, 0, stream>>>(esrc, edst, rows, cursor, col);

    // weights -> bf16 transposed; x -> bf16
    conv_wT<<<dim3(2,2,7), 256, 0, stream>>>(W1, W2, Wk, Wv, W3, W4, W5, Wts);
    conv_bf16<<<2500, 256, 0, stream>>>(x, xbf, NN*32);
    unsigned short* W1t = Wts;
    unsigned short* W2t = Wts + 16384;
    unsigned short* Wkt = Wts + 2*16384;
    unsigned short* Wvt = Wts + 3*16384;
    unsigned short* W4t = Wts + 5*16384;
    unsigned short* W5t = Wts + 6*16384;

    const int GN = 313;   // ceil(NN/64)
    const int GT = 625;   // NN/32
    const int GK = 32;    // ceil(KK/64) == KP/64

    // GCN1
    tgemm<<<GT, 256, 0, stream>>>(xbf, NN, W1t, dinv, ybuf);
    gcn_agg_bf<<<5000, 256, 0, stream>>>(ybuf, dinv, rows, col, b1, h1, 1, 0);
    // GCN2 -> h2
    tgemm<<<GT, 256, 0, stream>>>(h1, NN, W2t, dinv, ybuf);
    gcn_agg_bf<<<5000, 256, 0, stream>>>(ybuf, dinv, rows, col, b2, h2, 1, 0);
    // Kd -> Kbf (bf16)
    tgemm<<<GT, 256, 0, stream>>>(h2, NN, Wkt, dinv, ybuf);
    gcn_agg_bf<<<5000, 256, 0, stream>>>(ybuf, dinv, rows, col, bk, Kbf, 0, 0);
    // Q = S@Wq + bq (fp32) -> Qb + Qbf fused
    gemm128<<<GK, 512, 0, stream>>>(S, Wq, Qb, KK, bq, nullptr, 0, Qbf);
    // E = exp(SCALE * Kd Q^T), z partials
    s_gemm_exp<<<dim3(GN, 16), 256, 0, stream>>>(Kbf, Qbf, E, zpart);
    k_rcp32<<<79, 256, 0, stream>>>(zpart, dinv, zinv, zdinv);
    // Vd -> NB3 (fp32) -> Vtz (transposed bf16, pre-scaled by zinv[n])
    tgemm<<<GT, 256, 0, stream>>>(h2, NN, Wvt, dinv, ybuf);
    gcn_agg_bf<<<5000, 256, 0, stream>>>(ybuf, dinv, rows, col, bv, NB3, 0, 1);
    conv_bf16_T<<<dim3(GN, 2), 256, 0, stream>>>(NB3, Vtz, NN, NN, zinv);
    // attn partials (NB3 dead now; part aliases it)
    attn_gemm<<<dim3(GK, ZSPLIT), 256, 0, stream>>>(E, Vtz, part);
    // out = LN(sum(part) + Q)
    ln_ker<<<KK, 128, 0, stream>>>(part, ZSPLIT, Qb, g0, be0, o1);
    // o2 = o1 + relu(o1@Wo + bo)
    gemm128<<<GK, 512, 0, stream>>>(o1, Wo, o2, KK, bo, o1, 1, nullptr);
    ln_ker<<<KK, 128, 0, stream>>>(o2, 1, nullptr, g1, be1, o3);
    // xl = o3@Wl + bl ; xl3 = xl @ W3  (GCN3 weight folded into the seed side)
    gemm128<<<GK, 512, 0, stream>>>(o3, Wl, xlb, KK, bl, nullptr, 0, nullptr);
    gemm128<<<GK, 512, 0, stream>>>(xlb, W3, o1, KK, nullptr, nullptr, 0, nullptr);
    conv_bf16_T<<<dim3(GK, 2), 256, 0, stream>>>(o1, xlt3, KK, KP, nullptr);
    // ybuf[n] = bf16(zinv*dinv*(E[n] @ xl3))  == GCN3 pre-agg activations
    xout_gemm<<<dim3(GT, 2), 256, 0, stream>>>(E, xlt3, xpart);
    xred<<<2500, 256, 0, stream>>>(xpart, zdinv, ybuf);
    // GCN3 aggregation
    gcn_agg_bf<<<5000, 256, 0, stream>>>(ybuf, dinv, rows, col, b3, h3, 1, 0);
    // GCN4
    tgemm<<<GT, 256, 0, stream>>>(h3, NN, W4t, dinv, ybuf);
    gcn_agg_bf<<<5000, 256, 0, stream>>>(ybuf, dinv, rows, col, b4, h4, 1, 0);
    // GCN5 -> d_out (fp32)
    tgemm<<<GT, 256, 0, stream>>>(h4, NN, W5t, dinv, ybuf);
    gcn_agg_bf<<<5000, 256, 0, stream>>>(ybuf, dinv, rows, col, b5, outp, 0, 1);
}

// Round 12
// 661.024 us; speedup vs baseline: 1.0456x; 1.0268x over previous
//
#include <hip/hip_runtime.h>

#define NN 20000
#define EE 320000
#define KK 2000
#define KP 2048          // padded K-dim of E (zeros in 2000..2047)
#define SCALE 0.08838834764831845f
#define ZSPLIT 16        // attn_gemm partial slices
#define ACHUNKS 625      // 20000 / 32

typedef const float* cfp;
typedef __attribute__((ext_vector_type(8))) short sh8;
typedef __attribute__((ext_vector_type(4))) float f32x4;

static __device__ __forceinline__ float4 ld4(const float* p){ return *reinterpret_cast<const float4*>(p); }
static __device__ __forceinline__ void st4(float* p, float4 v){ *reinterpret_cast<float4*>(p) = v; }

static __device__ __forceinline__ unsigned short f2bf(float f){
    unsigned int u = __float_as_uint(f);
    u = (u + 0x7FFFu + ((u >> 16) & 1u)) >> 16;
    return (unsigned short)u;
}
static __device__ __forceinline__ float bf2f(unsigned short h){
    return __uint_as_float(((unsigned int)h) << 16);
}
static __device__ __forceinline__ sh8 lds8(const unsigned short* p){ return *reinterpret_cast<const sh8*>(p); }
static __device__ __forceinline__ sh8 ldnt8(const unsigned short* p){
    return __builtin_nontemporal_load(reinterpret_cast<const sh8*>(p));
}

// ---------------- CSR build ----------------
__global__ __launch_bounds__(256) void k_count(const int* dst, int* deg){
    int i = blockIdx.x*256 + threadIdx.x;
    if (i < EE) atomicAdd(&deg[dst[i]], 1);
}

__global__ __launch_bounds__(1024) void k_scan(const int* cnt, int* rows, float* dinv){
    __shared__ int part[1024];
    int t = threadIdx.x;
    int base = t*20;
    int s = 0;
    for (int i = 0; i < 20; ++i){ int idx = base+i; if (idx < NN) s += cnt[idx]; }
    part[t] = s; __syncthreads();
    for (int off = 1; off < 1024; off <<= 1){
        int v = (t >= off) ? part[t-off] : 0;
        __syncthreads();
        part[t] += v;
        __syncthreads();
    }
    int run = part[t] - s;   // exclusive
    for (int i = 0; i < 20; ++i){
        int idx = base+i;
        if (idx < NN){
            rows[idx] = run; run += cnt[idx];
            dinv[idx] = rsqrtf((float)cnt[idx] + 1.0f);
        }
    }
    if (t == 0) rows[NN] = EE;
}

__global__ __launch_bounds__(256) void k_fill(const int* src, const int* dst, const int* rows,
                                              int* cursor, int* col){
    int i = blockIdx.x*256 + threadIdx.x;
    if (i < EE){
        int d = dst[i];
        int pos = rows[d] + atomicAdd(&cursor[d], 1);
        col[pos] = src[i];
    }
}

// ---------------- weight transpose+convert ----------------
__global__ __launch_bounds__(256) void conv_wT(cfp w0, cfp w1, cfp w2, cfp w3, cfp w4, cfp w5, cfp w6,
                                               unsigned short* wts){
    const float* in;
    switch (blockIdx.z){
        case 0: in = w0; break; case 1: in = w1; break; case 2: in = w2; break;
        case 3: in = w3; break; case 4: in = w4; break; case 5: in = w5; break;
        default: in = w6; break;
    }
    unsigned short* out = wts + (size_t)blockIdx.z*16384;
    __shared__ float t[64][65];
    int r0 = blockIdx.x*64, c0 = blockIdx.y*64;
    int tid = threadIdx.x;
    for (int i = tid; i < 64*16; i += 256){
        int r = i >> 4, c4 = (i & 15) * 4;
        float4 v = ld4(in + (size_t)(r0+r)*128 + c0 + c4);
        t[r][c4+0]=v.x; t[r][c4+1]=v.y; t[r][c4+2]=v.z; t[r][c4+3]=v.w;
    }
    __syncthreads();
    for (int i = tid; i < 64*16; i += 256){
        int c = i >> 4, r4 = (i & 15) * 4;
        ushort4 o;
        o.x = f2bf(t[r4+0][c]); o.y = f2bf(t[r4+1][c]);
        o.z = f2bf(t[r4+2][c]); o.w = f2bf(t[r4+3][c]);
        *reinterpret_cast<ushort4*>(out + (size_t)(c0+c)*128 + r0 + r4) = o;
    }
}

// ---------------- fp32 GEMM (KK-sized only), optional bf16 dual-output ----------------
__global__ __launch_bounds__(512) void gemm128(const float* __restrict__ A, const float* __restrict__ Wm,
                                               float* __restrict__ C, int M,
                                               const float* bias, const float* resid, int relu,
                                               unsigned short* __restrict__ Cbf){
    __shared__ __align__(16) float Ws[128*132];
    __shared__ float As[64*129];
    int tid = threadIdx.x;
    int r0 = blockIdx.x*64;
    for (int i = tid; i < 128*32; i += 512){
        int r = i >> 5, c4 = (i & 31) * 4;
        float4 v = ld4(Wm + r*128 + c4);
        st4(&Ws[r*132 + c4], v);
    }
    for (int i = tid; i < 64*32; i += 512){
        int r = i >> 5, c4 = (i & 31) * 4;
        float4 v = (r0 + r < M) ? ld4(A + (size_t)(r0+r)*128 + c4) : make_float4(0,0,0,0);
        As[r*129 + c4+0] = v.x; As[r*129 + c4+1] = v.y;
        As[r*129 + c4+2] = v.z; As[r*129 + c4+3] = v.w;
    }
    __syncthreads();
    int a = tid >> 5;
    int b = tid & 31;
    float acc[4][4] = {};
    #pragma unroll 4
    for (int d = 0; d < 128; ++d){
        float4 w = ld4(&Ws[d*132 + 4*b]);
        float wv[4] = {w.x, w.y, w.z, w.w};
        float av[4];
        #pragma unroll
        for (int i = 0; i < 4; ++i) av[i] = As[(4*a+i)*129 + d];
        #pragma unroll
        for (int i = 0; i < 4; ++i)
            #pragma unroll
            for (int j = 0; j < 4; ++j)
                acc[i][j] += av[i]*wv[j];
    }
    int cc = 4*b;
    #pragma unroll
    for (int i = 0; i < 4; ++i){
        int r = r0 + 4*a + i;
        if (r < M){
            float v[4];
            #pragma unroll
            for (int j = 0; j < 4; ++j) v[j] = acc[i][j];
            if (bias){
                #pragma unroll
                for (int j = 0; j < 4; ++j) v[j] += bias[cc+j];
            }
            if (relu){
                #pragma unroll
                for (int j = 0; j < 4; ++j) v[j] = fmaxf(v[j], 0.f);
            }
            if (resid){
                float4 rv = ld4(resid + (size_t)r*128 + cc);
                v[0]+=rv.x; v[1]+=rv.y; v[2]+=rv.z; v[3]+=rv.w;
            }
            st4(C + (size_t)r*128 + cc, make_float4(v[0],v[1],v[2],v[3]));
            if (Cbf){
                ushort4 o;
                o.x = f2bf(v[0]); o.y = f2bf(v[1]); o.z = f2bf(v[2]); o.w = f2bf(v[3]);
                *reinterpret_cast<ushort4*>(Cbf + (size_t)r*128 + cc) = o;
            }
        }
    }
}

// ---------------- bf16 MFMA GEMM: 32m x 128n tiles, epilogue: *rscale + bias, bf16/fp32 out ----------------
__global__ __launch_bounds__(256) void tgemm(const unsigned short* __restrict__ A, int M,
                                             const unsigned short* __restrict__ Wt,
                                             const float* __restrict__ rscale,
                                             const float* __restrict__ bias,
                                             void* __restrict__ C, int out_fp32){
    int tid = threadIdx.x;
    int wave = tid >> 6, lane = tid & 63;
    int wm = wave >> 1, wn = wave & 1;
    int m_base = blockIdx.x*32 + wm*16;
    int l15 = lane & 15;
    int roff = (lane >> 4) * 8;
    const unsigned short* ap = A + (size_t)(m_base + l15)*128 + roff;
    const unsigned short* bp = Wt + (size_t)(wn*64 + l15)*128 + roff;
    f32x4 acc[4];
    #pragma unroll
    for (int j = 0; j < 4; ++j) acc[j] = (f32x4)0.f;
    #pragma unroll
    for (int r = 0; r < 128; r += 32){
        sh8 a = lds8(ap + r);
        #pragma unroll
        for (int j = 0; j < 4; ++j){
            sh8 b = lds8(bp + j*16*128 + r);
            acc[j] = __builtin_amdgcn_mfma_f32_16x16x32_bf16(a, b, acc[j], 0, 0, 0);
        }
    }
    int rq = (lane >> 4) * 4;
    #pragma unroll
    for (int ni = 0; ni < 4; ++ni){
        int gn = wn*64 + ni*16 + l15;
        float bv = bias ? bias[gn] : 0.f;
        #pragma unroll
        for (int reg = 0; reg < 4; ++reg){
            int gm = m_base + rq + reg;
            if (gm < M){
                float v = acc[ni][reg];
                if (rscale) v *= rscale[gm];
                v += bv;
                if (out_fp32) ((float*)C)[(size_t)gm*128 + gn] = v;
                else ((unsigned short*)C)[(size_t)gm*128 + gn] = f2bf(v);
            }
        }
    }
}

// ---------------- GCN aggregation (bf16 in, fp32 accumulate), neighbor unroll 8 ----------------
// out = act( dinv[n]*(y[n] + sum y[src]) + bias ) * (fold_dinv ? dinv[n] : 1)
__global__ __launch_bounds__(256) void gcn_agg_bf(const unsigned short* __restrict__ y, const float* __restrict__ dinv,
                                                  const int* __restrict__ rows, const int* __restrict__ col,
                                                  const float* __restrict__ bias, void* __restrict__ outv,
                                                  int relu, int out_fp32, int fold_dinv){
    int wid = (int)((blockIdx.x*256 + threadIdx.x) >> 6);
    int lane = threadIdx.x & 63;
    if (wid >= NN) return;
    int f = lane*2;
    ushort2 u = *reinterpret_cast<const ushort2*>(y + (size_t)wid*128 + f);
    float ax = bf2f(u.x), ay = bf2f(u.y);
    int s = rows[wid], e = rows[wid+1];
    int j = s;
    int e8 = s + ((e - s) & ~7);
    for (; j < e8; j += 8){
        ushort2 v[8];
        #pragma unroll
        for (int q = 0; q < 8; ++q){
            int c = col[j+q];
            v[q] = *reinterpret_cast<const ushort2*>(y + (size_t)c*128 + f);
        }
        #pragma unroll
        for (int q = 0; q < 8; ++q){ ax += bf2f(v[q].x); ay += bf2f(v[q].y); }
    }
    for (; j < e; ++j){
        int c0 = col[j];
        ushort2 v0 = *reinterpret_cast<const ushort2*>(y + (size_t)c0*128 + f);
        ax += bf2f(v0.x); ay += bf2f(v0.y);
    }
    float dn = dinv[wid];
    float ox = ax*dn + (bias ? bias[f]   : 0.f);
    float oy = ay*dn + (bias ? bias[f+1] : 0.f);
    if (relu){ ox = fmaxf(ox, 0.f); oy = fmaxf(oy, 0.f); }
    if (fold_dinv){ ox *= dn; oy *= dn; }
    if (out_fp32){
        *reinterpret_cast<float2*>((float*)outv + (size_t)wid*128 + f) = make_float2(ox, oy);
    } else {
        ushort2 o; o.x = f2bf(ox); o.y = f2bf(oy);
        *reinterpret_cast<ushort2*>((unsigned short*)outv + (size_t)wid*128 + f) = o;
    }
}

// ---------------- convert fp32 -> bf16 ----------------
__global__ __launch_bounds__(256) void conv_bf16(const float* __restrict__ in, unsigned short* __restrict__ out, int n4){
    int i = blockIdx.x*256 + threadIdx.x;
    if (i < n4){
        float4 v = ld4(in + (size_t)i*4);
        ushort4 o;
        o.x = f2bf(v.x); o.y = f2bf(v.y); o.z = f2bf(v.z); o.w = f2bf(v.w);
        *reinterpret_cast<ushort4*>(out + (size_t)i*4) = o;
    }
}

// ---------------- convert + transpose (+ optional per-source-row scale) ----------------
__global__ __launch_bounds__(256) void conv_bf16_T(const float* __restrict__ in, unsigned short* __restrict__ out,
                                                   int M, int ldout, const float* __restrict__ rscale){
    __shared__ float t[64][65];
    int r0 = blockIdx.x*64, c0 = blockIdx.y*64;
    int tid = threadIdx.x;
    for (int i = tid; i < 64*16; i += 256){
        int r = i >> 4, c4 = (i & 15) * 4;
        float4 v = (r0 + r < M) ? ld4(in + (size_t)(r0+r)*128 + c0 + c4) : make_float4(0,0,0,0);
        if (rscale && r0 + r < M){
            float sc = rscale[r0 + r];
            v.x *= sc; v.y *= sc; v.z *= sc; v.w *= sc;
        }
        t[r][c4+0]=v.x; t[r][c4+1]=v.y; t[r][c4+2]=v.z; t[r][c4+3]=v.w;
    }
    __syncthreads();
    for (int i = tid; i < 64*16; i += 256){
        int c = i >> 4, r4 = (i & 15) * 4;
        if (r0 + r4 < M){
            ushort4 o;
            o.x = f2bf(t[r4+0][c]); o.y = f2bf(t[r4+1][c]);
            o.z = f2bf(t[r4+2][c]); o.w = f2bf(t[r4+3][c]);
            *reinterpret_cast<ushort4*>(out + (size_t)(c0+c)*ldout + r0 + r4) = o;
        }
    }
}

// ---------------- z reduction: zinv[n] = 1/sum, zdinv[n] = zinv[n]*dinv[n] ----------------
__global__ __launch_bounds__(256) void k_rcp32(const float* __restrict__ zp, const float* __restrict__ dinv,
                                               float* __restrict__ zinv, float* __restrict__ zdinv){
    int n = blockIdx.x*256 + threadIdx.x;
    if (n < NN){
        float s = 0.f;
        #pragma unroll
        for (int y = 0; y < 16; ++y) s += zp[(size_t)y*NN + n];
        float zi = 1.f / s;
        zinv[n] = zi;
        zdinv[n] = zi * dinv[n];
    }
}

// ---------------- S-GEMM + exp + z-partials: 64n x 128k tiles, full-sector nt stores ----------------
__global__ __launch_bounds__(256) void s_gemm_exp(const unsigned short* __restrict__ Kb,
                                                  const unsigned short* __restrict__ Qb2,
                                                  unsigned short* __restrict__ E, float* __restrict__ zpart){
    __shared__ unsigned short Es[64*136];
    int tid = threadIdx.x;
    int wave = tid >> 6, lane = tid & 63;
    int wm = wave >> 1, wn = wave & 1;
    int n_blk = blockIdx.x*64, k_blk = blockIdx.y*128;
    int l15 = lane & 15;
    int roff = (lane >> 4) * 8;
    const unsigned short* ap0 = Kb + (size_t)(n_blk + wm*32 + l15)*128 + roff;
    const unsigned short* ap1 = ap0 + 16*128;
    const unsigned short* bp = Qb2 + (size_t)(k_blk + wn*64 + l15)*128 + roff;
    f32x4 acc[2][4];
    #pragma unroll
    for (int mi = 0; mi < 2; ++mi)
        #pragma unroll
        for (int j = 0; j < 4; ++j) acc[mi][j] = (f32x4)0.f;
    #pragma unroll
    for (int r = 0; r < 128; r += 32){
        sh8 a0 = lds8(ap0 + r);
        sh8 a1 = lds8(ap1 + r);
        #pragma unroll
        for (int j = 0; j < 4; ++j){
            sh8 b = lds8(bp + j*16*128 + r);
            acc[0][j] = __builtin_amdgcn_mfma_f32_16x16x32_bf16(a0, b, acc[0][j], 0, 0, 0);
            acc[1][j] = __builtin_amdgcn_mfma_f32_16x16x32_bf16(a1, b, acc[1][j], 0, 0, 0);
        }
    }
    int rq = (lane >> 4) * 4;
    #pragma unroll
    for (int mi = 0; mi < 2; ++mi){
        #pragma unroll
        for (int ni = 0; ni < 4; ++ni){
            f32x4 a = acc[mi][ni];
            int c_loc = wn*64 + ni*16 + l15;
            bool kv = (k_blk + c_loc) < KK;
            #pragma unroll
            for (int reg = 0; reg < 4; ++reg){
                int r_loc = wm*32 + mi*16 + rq + reg;
                float e = kv ? __expf(a[reg]*SCALE) : 0.f;
                Es[r_loc*136 + c_loc] = f2bf(e);
            }
        }
    }
    __syncthreads();
    if (tid < 64){
        int n = n_blk + tid;
        if (n < NN){
            float s = 0.f;
            #pragma unroll 8
            for (int j = 0; j < 128; ++j) s += bf2f(Es[tid*136 + j]);
            zpart[(size_t)blockIdx.y*NN + n] = s;
        }
    }
    // full 256B-per-row nontemporal store
    for (int i = tid; i < 1024; i += 256){
        int r = i >> 4, c8 = (i & 15) * 8;
        if (n_blk + r < NN){
            sh8 v = lds8(&Es[r*136 + c8]);
            union { sh8 s; unsigned long long q[2]; } u;
            u.s = v;
            unsigned long long* dst = reinterpret_cast<unsigned long long*>(E + (size_t)(n_blk + r)*KP + k_blk + c8);
            __builtin_nontemporal_store(u.q[0], dst);
            __builtin_nontemporal_store(u.q[1], dst + 1);
        }
    }
}

// ---------------- attn GEMM partials with next-chunk prefetch (nt E loads; exactly-once reads) ----------------
__global__ __launch_bounds__(256) void attn_gemm(const unsigned short* __restrict__ E,
                                                 const unsigned short* __restrict__ Vt,
                                                 float* __restrict__ part){
    __shared__ unsigned short As[64*36];
    int tid = threadIdx.x;
    int wave = tid >> 6, lane = tid & 63;
    int kk0 = blockIdx.x*64;
    int per = (ACHUNKS + ZSPLIT - 1) / ZSPLIT;
    int c0 = blockIdx.y*per;
    int c1 = min(ACHUNKS, c0 + per);
    int l15 = lane & 15;
    int q8 = (lane >> 4) * 8;
    int d0 = wave*32;
    int n_l = tid & 31;
    int k8 = (tid >> 5) * 8;
    f32x4 acc[4][2];
    #pragma unroll
    for (int g = 0; g < 4; ++g){ acc[g][0] = (f32x4)0.f; acc[g][1] = (f32x4)0.f; }
    const unsigned short* ebase = E + (size_t)n_l*KP + kk0 + k8;
    const unsigned short* vb0p = Vt + (size_t)(d0 + l15)*NN + q8;
    const unsigned short* vb1p = vb0p + (size_t)16*NN;
    sh8 etmp = ldnt8(ebase + (size_t)c0*32*KP);
    sh8 vb0 = lds8(vb0p + c0*32);
    sh8 vb1 = lds8(vb1p + c0*32);
    for (int ch = c0; ch < c1; ++ch){
        unsigned short tmp[8];
        *reinterpret_cast<sh8*>(tmp) = etmp;
        #pragma unroll
        for (int j = 0; j < 8; ++j) As[(k8 + j)*36 + n_l] = tmp[j];
        __syncthreads();
        sh8 etn = (sh8)0, vbn0 = (sh8)0, vbn1 = (sh8)0;
        if (ch + 1 < c1){
            etn  = ldnt8(ebase + (size_t)(ch+1)*32*KP);
            vbn0 = lds8(vb0p + (ch+1)*32);
            vbn1 = lds8(vb1p + (ch+1)*32);
        }
        #pragma unroll
        for (int g = 0; g < 4; ++g){
            const unsigned short* ap = &As[(g*16 + l15)*36 + q8];
            union { struct { ushort4 lo, hi; } u; sh8 v; } af;
            af.u.lo = *reinterpret_cast<const ushort4*>(ap);
            af.u.hi = *reinterpret_cast<const ushort4*>(ap + 4);
            acc[g][0] = __builtin_amdgcn_mfma_f32_16x16x32_bf16(af.v, vb0, acc[g][0], 0, 0, 0);
            acc[g][1] = __builtin_amdgcn_mfma_f32_16x16x32_bf16(af.v, vb1, acc[g][1], 0, 0, 0);
        }
        __syncthreads();
        etmp = etn; vb0 = vbn0; vb1 = vbn1;
    }
    float* pbase = part + (size_t)blockIdx.y*KK*128;
    int rq = (lane >> 4) * 4;
    #pragma unroll
    for (int g = 0; g < 4; ++g){
        #pragma unroll
        for (int ni = 0; ni < 2; ++ni){
            int d = d0 + ni*16 + l15;
            #pragma unroll
            for (int reg = 0; reg < 4; ++reg){
                int kk = kk0 + g*16 + rq + reg;
                if (kk < KK) pbase[(size_t)kk*128 + d] = acc[g][ni][reg];
            }
        }
    }
}

// ---------------- xout GEMM: 32m x 128n tiles, K-split x2, depth-4 E pipeline ----------------
__global__ __launch_bounds__(256) void xout_gemm(const unsigned short* __restrict__ E,
                                                 const unsigned short* __restrict__ B,
                                                 float* __restrict__ xpart){
    int tid = threadIdx.x;
    int wave = tid >> 6, lane = tid & 63;
    int wm = wave >> 1, wn = wave & 1;
    int m_base = blockIdx.x*32 + wm*16;
    int kz = blockIdx.y*1024;
    int l15 = lane & 15;
    int roff = (lane >> 4) * 8;
    const unsigned short* ap = E + (size_t)(m_base + l15)*KP + kz + roff;
    const unsigned short* bp = B + (size_t)(wn*64 + l15)*KP + kz + roff;
    f32x4 acc[4];
    #pragma unroll
    for (int j = 0; j < 4; ++j) acc[j] = (f32x4)0.f;
    // prime: E chunk 0 (4 batches in flight), B batch 0
    sh8 e0 = lds8(ap), e1 = lds8(ap + 32), e2 = lds8(ap + 64), e3 = lds8(ap + 96);
    sh8 b0 = lds8(bp), b1 = lds8(bp + 16*KP), b2 = lds8(bp + 32*KP), b3 = lds8(bp + 48*KP);
    for (int c = 0; c < 8; ++c){
        int rc = c*128;
        sh8 f0 = (sh8)0, f1 = (sh8)0, f2 = (sh8)0, f3 = (sh8)0;
        if (c < 7){
            f0 = lds8(ap + rc + 128); f1 = lds8(ap + rc + 160);
            f2 = lds8(ap + rc + 192); f3 = lds8(ap + rc + 224);
        }
        #pragma unroll
        for (int s = 0; s < 4; ++s){
            sh8 ecur = (s == 0) ? e0 : ((s == 1) ? e1 : ((s == 2) ? e2 : e3));
            int rn = rc + (s + 1)*32;
            sh8 nb0 = (sh8)0, nb1 = (sh8)0, nb2 = (sh8)0, nb3 = (sh8)0;
            if (rn < 1024){
                nb0 = lds8(bp + rn);           nb1 = lds8(bp + 16*KP + rn);
                nb2 = lds8(bp + 32*KP + rn);   nb3 = lds8(bp + 48*KP + rn);
            }
            acc[0] = __builtin_amdgcn_mfma_f32_16x16x32_bf16(ecur, b0, acc[0], 0, 0, 0);
            acc[1] = __builtin_amdgcn_mfma_f32_16x16x32_bf16(ecur, b1, acc[1], 0, 0, 0);
            acc[2] = __builtin_amdgcn_mfma_f32_16x16x32_bf16(ecur, b2, acc[2], 0, 0, 0);
            acc[3] = __builtin_amdgcn_mfma_f32_16x16x32_bf16(ecur, b3, acc[3], 0, 0, 0);
            b0 = nb0; b1 = nb1; b2 = nb2; b3 = nb3;
        }
        e0 = f0; e1 = f1; e2 = f2; e3 = f3;
    }
    float* pbase = xpart + (size_t)blockIdx.y*NN*128;
    int rq = (lane >> 4) * 4;
    #pragma unroll
    for (int ni = 0; ni < 4; ++ni){
        int gn = wn*64 + ni*16 + l15;
        #pragma unroll
        for (int reg = 0; reg < 4; ++reg){
            int gm = m_base + rq + reg;
            if (gm < NN) pbase[(size_t)gm*128 + gn] = acc[ni][reg];
        }
    }
}

// ---------------- xout reduce: ybuf = bf16(zdinv[n] * (p0 + p1)) ----------------
__global__ __launch_bounds__(256) void xred(const float* __restrict__ xp, const float* __restrict__ zdinv,
                                            unsigned short* __restrict__ out){
    int i = blockIdx.x*256 + threadIdx.x;
    if (i < NN*32){
        int row = i >> 5;
        float4 p0 = ld4(xp + (size_t)i*4);
        float4 p1 = ld4(xp + (size_t)NN*128 + (size_t)i*4);
        float sc = zdinv[row];
        ushort4 o;
        o.x = f2bf((p0.x + p1.x)*sc);
        o.y = f2bf((p0.y + p1.y)*sc);
        o.z = f2bf((p0.z + p1.z)*sc);
        o.w = f2bf((p0.w + p1.w)*sc);
        *reinterpret_cast<ushort4*>(out + (size_t)i*4) = o;
    }
}

// ---------------- LayerNorm over D=128 (with partial-sum input) ----------------
__global__ __launch_bounds__(128) void ln_ker(const float* __restrict__ in, int nparts,
                                              const float* __restrict__ resid,
                                              const float* __restrict__ g, const float* __restrict__ be,
                                              float* __restrict__ out){
    __shared__ float rs[128], rq[128];
    int r = blockIdx.x, t = threadIdx.x;
    float v = 0.f;
    for (int p = 0; p < nparts; ++p) v += in[(size_t)p*KK*128 + r*128 + t];
    if (resid) v += resid[r*128 + t];
    rs[t] = v; rq[t] = v*v;
    __syncthreads();
    for (int off = 64; off > 0; off >>= 1){
        if (t < off){ rs[t] += rs[t+off]; rq[t] += rq[t+off]; }
        __syncthreads();
    }
    float mean = rs[0]*(1.f/128.f);
    float var = rq[0]*(1.f/128.f) - mean*mean;
    out[r*128 + t] = (v - mean)*rsqrtf(var + 1e-5f)*g[t] + be[t];
}

// ---------------- launcher ----------------
extern "C" void kernel_launch(void* const* d_in, const int* in_sizes, int n_in,
                              void* d_out, int out_size, void* d_ws, size_t ws_size,
                              hipStream_t stream){
    cfp x  = (cfp)d_in[0];
    const int* ei = (const int*)d_in[1];
    const int* esrc = ei;
    const int* edst = ei + EE;
    cfp W1=(cfp)d_in[3], b1=(cfp)d_in[4], W2=(cfp)d_in[5], b2=(cfp)d_in[6];
    cfp S =(cfp)d_in[7];
    cfp Wq=(cfp)d_in[8],  bq=(cfp)d_in[9],  Wk=(cfp)d_in[10], bk=(cfp)d_in[11];
    cfp Wv=(cfp)d_in[12], bv=(cfp)d_in[13], Wo=(cfp)d_in[14], bo=(cfp)d_in[15];
    cfp g0=(cfp)d_in[16], be0=(cfp)d_in[17], g1=(cfp)d_in[18], be1=(cfp)d_in[19];
    cfp Wl=(cfp)d_in[20], bl=(cfp)d_in[21], W3=(cfp)d_in[22], b3=(cfp)d_in[23];
    cfp W4=(cfp)d_in[24], b4=(cfp)d_in[25], W5=(cfp)d_in[26], b5=(cfp)d_in[27];

    char* wsb = (char*)d_ws;
    const size_t MB = 1048576;
    int*   deg    = (int*)  (wsb + 0);
    float* dinv   = (float*)(wsb + 81920);
    int*   rows   = (int*)  (wsb + 163840);
    int*   cursor = (int*)  (wsb + 245760);
    int*   col    = (int*)  (wsb + 327680);          // ends at 1607680
    float* zeros  = (float*)(wsb + 1703936);         // 512B-aligned zero bias
    float* Qb     = (float*)(wsb + 2*MB);
    float* o1     = (float*)(wsb + 3*MB);    // also xl3 (fp32)
    float* o2     = (float*)(wsb + 4*MB);
    float* o3     = (float*)(wsb + 5*MB);
    float* xlb    = (float*)(wsb + 6*MB);
    float* zpart  = (float*)(wsb + 7*MB);                 // 16 x NN fp32
    float* zinv   = (float*)(wsb + 10*MB);
    float* zdinv  = (float*)(wsb + 10*MB + 131072);
    unsigned short* Wts  = (unsigned short*)(wsb + 10*MB + 262144);
    unsigned short* Qbf  = (unsigned short*)(wsb + 11*MB);
    unsigned short* xlt3 = (unsigned short*)(wsb + 11*MB + 524288);  // [128 x KP] bf16
    unsigned short* xbf = (unsigned short*)(wsb + 12*MB); // also h3
    unsigned short* h1  = (unsigned short*)(wsb + 17*MB); // also g2, h4
    unsigned short* h2s = (unsigned short*)(wsb + 22*MB);
    unsigned short* ybuf= (unsigned short*)(wsb + 27*MB);
    unsigned short* Kbf = (unsigned short*)(wsb + 32*MB);
    unsigned short* Vtz = (unsigned short*)(wsb + 37*MB);
    // time-aliased region 42..62 MiB: NB3 (Vd fp32) -> part (16 MiB) -> xpart (19.6 MiB)
    float* NB3    = (float*)(wsb + 42*MB);
    float* part   = (float*)(wsb + 42*MB);
    float* xpart  = (float*)(wsb + 42*MB);
    unsigned short* E = (unsigned short*)(wsb + 62*MB);   // [NN x KP] bf16 = 78.1 MiB
    float* outp   = (float*)d_out;
    unsigned short* g2 = h1;    // h1 dead after GCN2 tgemm
    unsigned short* h3 = xbf;
    unsigned short* h4 = h1;

    (void)hipMemsetAsync(deg, 0, NN*sizeof(int), stream);
    (void)hipMemsetAsync(cursor, 0, NN*sizeof(int), stream);
    (void)hipMemsetAsync(zeros, 0, 512, stream);
    (void)hipMemsetAsync(xlt3, 0, 128*KP*sizeof(unsigned short), stream);  // pad cols must be finite

    // CSR build
    k_count<<<1250, 256, 0, stream>>>(edst, deg);
    k_scan<<<1, 1024, 0, stream>>>(deg, rows, dinv);
    k_fill<<<1250, 256, 0, stream>>>(esrc, edst, rows, cursor, col);

    // weights -> bf16 transposed; x -> bf16
    conv_wT<<<dim3(2,2,7), 256, 0, stream>>>(W1, W2, Wk, Wv, W3, W4, W5, Wts);
    conv_bf16<<<2500, 256, 0, stream>>>(x, xbf, NN*32);
    unsigned short* W1t = Wts;
    unsigned short* W2t = Wts + 16384;
    unsigned short* Wkt = Wts + 2*16384;
    unsigned short* Wvt = Wts + 3*16384;
    unsigned short* W4t = Wts + 5*16384;
    unsigned short* W5t = Wts + 6*16384;

    const int GN = 313;   // ceil(NN/64)
    const int GT = 625;   // NN/32
    const int GK = 32;    // ceil(KK/64) == KP/64

    // GCN1
    tgemm<<<GT, 256, 0, stream>>>(xbf, NN, W1t, dinv, nullptr, h1, 0);           // pre-scaled rows
    gcn_agg_bf<<<5000, 256, 0, stream>>>(h1, dinv, rows, col, b1, ybuf, 1, 0, 0);
    // GCN2 -> h2s = relu(.)·dinv (fold for shared K/V aggregation)
    tgemm<<<GT, 256, 0, stream>>>(ybuf, NN, W2t, dinv, nullptr, h1, 0);
    gcn_agg_bf<<<5000, 256, 0, stream>>>(h1, dinv, rows, col, b2, h2s, 1, 0, 1);
    // g2 = dinv·(h2s + sum h2s[src])  (single aggregation shared by K and V)
    gcn_agg_bf<<<5000, 256, 0, stream>>>(h2s, dinv, rows, col, zeros, g2, 0, 0, 0);
    // Kd = g2@Wk + bk (bf16)
    tgemm<<<GT, 256, 0, stream>>>(g2, NN, Wkt, nullptr, bk, Kbf, 0);
    // Q = S@Wq + bq (fp32) -> Qb + Qbf fused
    gemm128<<<GK, 512, 0, stream>>>(S, Wq, Qb, KK, bq, nullptr, 0, Qbf);
    // E = exp(SCALE * Kd Q^T), z partials
    s_gemm_exp<<<dim3(GN, 16), 256, 0, stream>>>(Kbf, Qbf, E, zpart);
    k_rcp32<<<79, 256, 0, stream>>>(zpart, dinv, zinv, zdinv);
    // Vd = g2@Wv + bv (fp32) -> Vtz (transposed bf16, pre-scaled by zinv[n])
    tgemm<<<GT, 256, 0, stream>>>(g2, NN, Wvt, nullptr, bv, NB3, 1);
    conv_bf16_T<<<dim3(GN, 2), 256, 0, stream>>>(NB3, Vtz, NN, NN, zinv);
    // attn partials (NB3 dead now; part aliases it)
    attn_gemm<<<dim3(GK, ZSPLIT), 256, 0, stream>>>(E, Vtz, part);
    // out = LN(sum(part) + Q)
    ln_ker<<<KK, 128, 0, stream>>>(part, ZSPLIT, Qb, g0, be0, o1);
    // o2 = o1 + relu(o1@Wo + bo)
    gemm128<<<GK, 512, 0, stream>>>(o1, Wo, o2, KK, bo, o1, 1, nullptr);
    ln_ker<<<KK, 128, 0, stream>>>(o2, 1, nullptr, g1, be1, o3);
    // xl = o3@Wl + bl ; xl3 = xl @ W3  (GCN3 weight folded into the seed side)
    gemm128<<<GK, 512, 0, stream>>>(o3, Wl, xlb, KK, bl, nullptr, 0, nullptr);
    gemm128<<<GK, 512, 0, stream>>>(xlb, W3, o1, KK, nullptr, nullptr, 0, nullptr);
    conv_bf16_T<<<dim3(GK, 2), 256, 0, stream>>>(o1, xlt3, KK, KP, nullptr);
    // ybuf[n] = bf16(zinv*dinv*(E[n] @ xl3))  == GCN3 pre-agg activations
    xout_gemm<<<dim3(GT, 2), 256, 0, stream>>>(E, xlt3, xpart);
    xred<<<2500, 256, 0, stream>>>(xpart, zdinv, ybuf);
    // GCN3 aggregation
    gcn_agg_bf<<<5000, 256, 0, stream>>>(ybuf, dinv, rows, col, b3, h3, 1, 0, 0);
    // GCN4
    tgemm<<<GT, 256, 0, stream>>>(h3, NN, W4t, dinv, nullptr, ybuf, 0);
    gcn_agg_bf<<<5000, 256, 0, stream>>>(ybuf, dinv, rows, col, b4, h4, 1, 0, 0);
    // GCN5 -> d_out (fp32)
    tgemm<<<GT, 256, 0, stream>>>(h4, NN, W5t, dinv, nullptr, ybuf, 0);
    gcn_agg_bf<<<5000, 256, 0, stream>>>(ybuf, dinv, rows, col, b5, outp, 0, 1, 0);
}

// Round 13
// 660.999 us; speedup vs baseline: 1.0456x; 1.0000x over previous
//
#include <hip/hip_runtime.h>

#define NN 20000
#define EE 320000
#define KK 2000
#define KP 2048          // padded K-dim of E (zeros in 2000..2047)
#define SCALE 0.08838834764831845f
#define ZSPLIT 16        // attn_gemm partial slices
#define ACHUNKS 625      // 20000 / 32

typedef const float* cfp;
typedef __attribute__((ext_vector_type(8))) short sh8;
typedef __attribute__((ext_vector_type(4))) float f32x4;

static __device__ __forceinline__ float4 ld4(const float* p){ return *reinterpret_cast<const float4*>(p); }
static __device__ __forceinline__ void st4(float* p, float4 v){ *reinterpret_cast<float4*>(p) = v; }

static __device__ __forceinline__ unsigned short f2bf(float f){
    unsigned int u = __float_as_uint(f);
    u = (u + 0x7FFFu + ((u >> 16) & 1u)) >> 16;
    return (unsigned short)u;
}
static __device__ __forceinline__ float bf2f(unsigned short h){
    return __uint_as_float(((unsigned int)h) << 16);
}
static __device__ __forceinline__ sh8 lds8(const unsigned short* p){ return *reinterpret_cast<const sh8*>(p); }
static __device__ __forceinline__ sh8 ldnt8(const unsigned short* p){
    return __builtin_nontemporal_load(reinterpret_cast<const sh8*>(p));
}

// ---------------- CSR build ----------------
__global__ __launch_bounds__(256) void k_count(const int* dst, int* deg){
    int i = blockIdx.x*256 + threadIdx.x;
    if (i < EE) atomicAdd(&deg[dst[i]], 1);
}

__global__ __launch_bounds__(1024) void k_scan(const int* cnt, int* rows, float* dinv){
    __shared__ int part[1024];
    int t = threadIdx.x;
    int base = t*20;
    int s = 0;
    for (int i = 0; i < 20; ++i){ int idx = base+i; if (idx < NN) s += cnt[idx]; }
    part[t] = s; __syncthreads();
    for (int off = 1; off < 1024; off <<= 1){
        int v = (t >= off) ? part[t-off] : 0;
        __syncthreads();
        part[t] += v;
        __syncthreads();
    }
    int run = part[t] - s;   // exclusive
    for (int i = 0; i < 20; ++i){
        int idx = base+i;
        if (idx < NN){
            rows[idx] = run; run += cnt[idx];
            dinv[idx] = rsqrtf((float)cnt[idx] + 1.0f);
        }
    }
    if (t == 0) rows[NN] = EE;
}

__global__ __launch_bounds__(256) void k_fill(const int* src, const int* dst, const int* rows,
                                              int* cursor, int* col){
    int i = blockIdx.x*256 + threadIdx.x;
    if (i < EE){
        int d = dst[i];
        int pos = rows[d] + atomicAdd(&cursor[d], 1);
        col[pos] = src[i];
    }
}

// ---------------- weight transpose+convert ----------------
__global__ __launch_bounds__(256) void conv_wT(cfp w0, cfp w1, cfp w2, cfp w3, cfp w4, cfp w5, cfp w6,
                                               unsigned short* wts){
    const float* in;
    switch (blockIdx.z){
        case 0: in = w0; break; case 1: in = w1; break; case 2: in = w2; break;
        case 3: in = w3; break; case 4: in = w4; break; case 5: in = w5; break;
        default: in = w6; break;
    }
    unsigned short* out = wts + (size_t)blockIdx.z*16384;
    __shared__ float t[64][65];
    int r0 = blockIdx.x*64, c0 = blockIdx.y*64;
    int tid = threadIdx.x;
    for (int i = tid; i < 64*16; i += 256){
        int r = i >> 4, c4 = (i & 15) * 4;
        float4 v = ld4(in + (size_t)(r0+r)*128 + c0 + c4);
        t[r][c4+0]=v.x; t[r][c4+1]=v.y; t[r][c4+2]=v.z; t[r][c4+3]=v.w;
    }
    __syncthreads();
    for (int i = tid; i < 64*16; i += 256){
        int c = i >> 4, r4 = (i & 15) * 4;
        ushort4 o;
        o.x = f2bf(t[r4+0][c]); o.y = f2bf(t[r4+1][c]);
        o.z = f2bf(t[r4+2][c]); o.w = f2bf(t[r4+3][c]);
        *reinterpret_cast<ushort4*>(out + (size_t)(c0+c)*128 + r0 + r4) = o;
    }
}

// ---------------- fp32 GEMM (KK-sized only), optional bf16 dual-output ----------------
__global__ __launch_bounds__(512) void gemm128(const float* __restrict__ A, const float* __restrict__ Wm,
                                               float* __restrict__ C, int M,
                                               const float* bias, const float* resid, int relu,
                                               unsigned short* __restrict__ Cbf){
    __shared__ __align__(16) float Ws[128*132];
    __shared__ float As[64*129];
    int tid = threadIdx.x;
    int r0 = blockIdx.x*64;
    for (int i = tid; i < 128*32; i += 512){
        int r = i >> 5, c4 = (i & 31) * 4;
        float4 v = ld4(Wm + r*128 + c4);
        st4(&Ws[r*132 + c4], v);
    }
    for (int i = tid; i < 64*32; i += 512){
        int r = i >> 5, c4 = (i & 31) * 4;
        float4 v = (r0 + r < M) ? ld4(A + (size_t)(r0+r)*128 + c4) : make_float4(0,0,0,0);
        As[r*129 + c4+0] = v.x; As[r*129 + c4+1] = v.y;
        As[r*129 + c4+2] = v.z; As[r*129 + c4+3] = v.w;
    }
    __syncthreads();
    int a = tid >> 5;
    int b = tid & 31;
    float acc[4][4] = {};
    #pragma unroll 4
    for (int d = 0; d < 128; ++d){
        float4 w = ld4(&Ws[d*132 + 4*b]);
        float wv[4] = {w.x, w.y, w.z, w.w};
        float av[4];
        #pragma unroll
        for (int i = 0; i < 4; ++i) av[i] = As[(4*a+i)*129 + d];
        #pragma unroll
        for (int i = 0; i < 4; ++i)
            #pragma unroll
            for (int j = 0; j < 4; ++j)
                acc[i][j] += av[i]*wv[j];
    }
    int cc = 4*b;
    #pragma unroll
    for (int i = 0; i < 4; ++i){
        int r = r0 + 4*a + i;
        if (r < M){
            float v[4];
            #pragma unroll
            for (int j = 0; j < 4; ++j) v[j] = acc[i][j];
            if (bias){
                #pragma unroll
                for (int j = 0; j < 4; ++j) v[j] += bias[cc+j];
            }
            if (relu){
                #pragma unroll
                for (int j = 0; j < 4; ++j) v[j] = fmaxf(v[j], 0.f);
            }
            if (resid){
                float4 rv = ld4(resid + (size_t)r*128 + cc);
                v[0]+=rv.x; v[1]+=rv.y; v[2]+=rv.z; v[3]+=rv.w;
            }
            st4(C + (size_t)r*128 + cc, make_float4(v[0],v[1],v[2],v[3]));
            if (Cbf){
                ushort4 o;
                o.x = f2bf(v[0]); o.y = f2bf(v[1]); o.z = f2bf(v[2]); o.w = f2bf(v[3]);
                *reinterpret_cast<ushort4*>(Cbf + (size_t)r*128 + cc) = o;
            }
        }
    }
}

// ---------------- bf16 MFMA GEMM: 32m x 128n tiles, epilogue: *rscale + bias, bf16/fp32 out ----------------
__global__ __launch_bounds__(256) void tgemm(const unsigned short* __restrict__ A, int M,
                                             const unsigned short* __restrict__ Wt,
                                             const float* __restrict__ rscale,
                                             const float* __restrict__ bias,
                                             void* __restrict__ C, int out_fp32){
    int tid = threadIdx.x;
    int wave = tid >> 6, lane = tid & 63;
    int wm = wave >> 1, wn = wave & 1;
    int m_base = blockIdx.x*32 + wm*16;
    int l15 = lane & 15;
    int roff = (lane >> 4) * 8;
    const unsigned short* ap = A + (size_t)(m_base + l15)*128 + roff;
    const unsigned short* bp = Wt + (size_t)(wn*64 + l15)*128 + roff;
    f32x4 acc[4];
    #pragma unroll
    for (int j = 0; j < 4; ++j) acc[j] = (f32x4)0.f;
    #pragma unroll
    for (int r = 0; r < 128; r += 32){
        sh8 a = lds8(ap + r);
        #pragma unroll
        for (int j = 0; j < 4; ++j){
            sh8 b = lds8(bp + j*16*128 + r);
            acc[j] = __builtin_amdgcn_mfma_f32_16x16x32_bf16(a, b, acc[j], 0, 0, 0);
        }
    }
    int rq = (lane >> 4) * 4;
    #pragma unroll
    for (int ni = 0; ni < 4; ++ni){
        int gn = wn*64 + ni*16 + l15;
        float bv = bias ? bias[gn] : 0.f;
        #pragma unroll
        for (int reg = 0; reg < 4; ++reg){
            int gm = m_base + rq + reg;
            if (gm < M){
                float v = acc[ni][reg];
                if (rscale) v *= rscale[gm];
                v += bv;
                if (out_fp32) ((float*)C)[(size_t)gm*128 + gn] = v;
                else ((unsigned short*)C)[(size_t)gm*128 + gn] = f2bf(v);
            }
        }
    }
}

// ---------------- GCN aggregation (bf16 in, fp32 accumulate), neighbor unroll 8 ----------------
__global__ __launch_bounds__(256) void gcn_agg_bf(const unsigned short* __restrict__ y, const float* __restrict__ dinv,
                                                  const int* __restrict__ rows, const int* __restrict__ col,
                                                  const float* __restrict__ bias, void* __restrict__ outv,
                                                  int relu, int out_fp32, int fold_dinv){
    int wid = (int)((blockIdx.x*256 + threadIdx.x) >> 6);
    int lane = threadIdx.x & 63;
    if (wid >= NN) return;
    int f = lane*2;
    ushort2 u = *reinterpret_cast<const ushort2*>(y + (size_t)wid*128 + f);
    float ax = bf2f(u.x), ay = bf2f(u.y);
    int s = rows[wid], e = rows[wid+1];
    int j = s;
    int e8 = s + ((e - s) & ~7);
    for (; j < e8; j += 8){
        ushort2 v[8];
        #pragma unroll
        for (int q = 0; q < 8; ++q){
            int c = col[j+q];
            v[q] = *reinterpret_cast<const ushort2*>(y + (size_t)c*128 + f);
        }
        #pragma unroll
        for (int q = 0; q < 8; ++q){ ax += bf2f(v[q].x); ay += bf2f(v[q].y); }
    }
    for (; j < e; ++j){
        int c0 = col[j];
        ushort2 v0 = *reinterpret_cast<const ushort2*>(y + (size_t)c0*128 + f);
        ax += bf2f(v0.x); ay += bf2f(v0.y);
    }
    float dn = dinv[wid];
    float ox = ax*dn + (bias ? bias[f]   : 0.f);
    float oy = ay*dn + (bias ? bias[f+1] : 0.f);
    if (relu){ ox = fmaxf(ox, 0.f); oy = fmaxf(oy, 0.f); }
    if (fold_dinv){ ox *= dn; oy *= dn; }
    if (out_fp32){
        *reinterpret_cast<float2*>((float*)outv + (size_t)wid*128 + f) = make_float2(ox, oy);
    } else {
        ushort2 o; o.x = f2bf(ox); o.y = f2bf(oy);
        *reinterpret_cast<ushort2*>((unsigned short*)outv + (size_t)wid*128 + f) = o;
    }
}

// ---------------- convert fp32 -> bf16 ----------------
__global__ __launch_bounds__(256) void conv_bf16(const float* __restrict__ in, unsigned short* __restrict__ out, int n4){
    int i = blockIdx.x*256 + threadIdx.x;
    if (i < n4){
        float4 v = ld4(in + (size_t)i*4);
        ushort4 o;
        o.x = f2bf(v.x); o.y = f2bf(v.y); o.z = f2bf(v.z); o.w = f2bf(v.w);
        *reinterpret_cast<ushort4*>(out + (size_t)i*4) = o;
    }
}

// ---------------- convert + transpose (+ optional per-source-row scale) ----------------
__global__ __launch_bounds__(256) void conv_bf16_T(const float* __restrict__ in, unsigned short* __restrict__ out,
                                                   int M, int ldout, const float* __restrict__ rscale){
    __shared__ float t[64][65];
    int r0 = blockIdx.x*64, c0 = blockIdx.y*64;
    int tid = threadIdx.x;
    for (int i = tid; i < 64*16; i += 256){
        int r = i >> 4, c4 = (i & 15) * 4;
        float4 v = (r0 + r < M) ? ld4(in + (size_t)(r0+r)*128 + c0 + c4) : make_float4(0,0,0,0);
        if (rscale && r0 + r < M){
            float sc = rscale[r0 + r];
            v.x *= sc; v.y *= sc; v.z *= sc; v.w *= sc;
        }
        t[r][c4+0]=v.x; t[r][c4+1]=v.y; t[r][c4+2]=v.z; t[r][c4+3]=v.w;
    }
    __syncthreads();
    for (int i = tid; i < 64*16; i += 256){
        int c = i >> 4, r4 = (i & 15) * 4;
        if (r0 + r4 < M){
            ushort4 o;
            o.x = f2bf(t[r4+0][c]); o.y = f2bf(t[r4+1][c]);
            o.z = f2bf(t[r4+2][c]); o.w = f2bf(t[r4+3][c]);
            *reinterpret_cast<ushort4*>(out + (size_t)(c0+c)*ldout + r0 + r4) = o;
        }
    }
}

// ---------------- z reduction: zinv[n] = 1/sum, zdinv[n] = zinv[n]*dinv[n] ----------------
__global__ __launch_bounds__(256) void k_rcp32(const float* __restrict__ zp, const float* __restrict__ dinv,
                                               float* __restrict__ zinv, float* __restrict__ zdinv){
    int n = blockIdx.x*256 + threadIdx.x;
    if (n < NN){
        float s = 0.f;
        #pragma unroll
        for (int y = 0; y < 16; ++y) s += zp[(size_t)y*NN + n];
        float zi = 1.f / s;
        zinv[n] = zi;
        zdinv[n] = zi * dinv[n];
    }
}

// ---------------- S-GEMM + exp + z-partials: 64n x 128k tiles, full-sector nt stores ----------------
__global__ __launch_bounds__(256) void s_gemm_exp(const unsigned short* __restrict__ Kb,
                                                  const unsigned short* __restrict__ Qb2,
                                                  unsigned short* __restrict__ E, float* __restrict__ zpart){
    __shared__ unsigned short Es[64*136];
    int tid = threadIdx.x;
    int wave = tid >> 6, lane = tid & 63;
    int wm = wave >> 1, wn = wave & 1;
    int n_blk = blockIdx.x*64, k_blk = blockIdx.y*128;
    int l15 = lane & 15;
    int roff = (lane >> 4) * 8;
    const unsigned short* ap0 = Kb + (size_t)(n_blk + wm*32 + l15)*128 + roff;
    const unsigned short* ap1 = ap0 + 16*128;
    const unsigned short* bp = Qb2 + (size_t)(k_blk + wn*64 + l15)*128 + roff;
    f32x4 acc[2][4];
    #pragma unroll
    for (int mi = 0; mi < 2; ++mi)
        #pragma unroll
        for (int j = 0; j < 4; ++j) acc[mi][j] = (f32x4)0.f;
    #pragma unroll
    for (int r = 0; r < 128; r += 32){
        sh8 a0 = lds8(ap0 + r);
        sh8 a1 = lds8(ap1 + r);
        #pragma unroll
        for (int j = 0; j < 4; ++j){
            sh8 b = lds8(bp + j*16*128 + r);
            acc[0][j] = __builtin_amdgcn_mfma_f32_16x16x32_bf16(a0, b, acc[0][j], 0, 0, 0);
            acc[1][j] = __builtin_amdgcn_mfma_f32_16x16x32_bf16(a1, b, acc[1][j], 0, 0, 0);
        }
    }
    int rq = (lane >> 4) * 4;
    #pragma unroll
    for (int mi = 0; mi < 2; ++mi){
        #pragma unroll
        for (int ni = 0; ni < 4; ++ni){
            f32x4 a = acc[mi][ni];
            int c_loc = wn*64 + ni*16 + l15;
            bool kv = (k_blk + c_loc) < KK;
            #pragma unroll
            for (int reg = 0; reg < 4; ++reg){
                int r_loc = wm*32 + mi*16 + rq + reg;
                float e = kv ? __expf(a[reg]*SCALE) : 0.f;
                Es[r_loc*136 + c_loc] = f2bf(e);
            }
        }
    }
    __syncthreads();
    if (tid < 64){
        int n = n_blk + tid;
        if (n < NN){
            float s = 0.f;
            #pragma unroll 8
            for (int j = 0; j < 128; ++j) s += bf2f(Es[tid*136 + j]);
            zpart[(size_t)blockIdx.y*NN + n] = s;
        }
    }
    // full 256B-per-row nontemporal store
    for (int i = tid; i < 1024; i += 256){
        int r = i >> 4, c8 = (i & 15) * 8;
        if (n_blk + r < NN){
            sh8 v = lds8(&Es[r*136 + c8]);
            union { sh8 s; unsigned long long q[2]; } u;
            u.s = v;
            unsigned long long* dst = reinterpret_cast<unsigned long long*>(E + (size_t)(n_blk + r)*KP + k_blk + c8);
            __builtin_nontemporal_store(u.q[0], dst);
            __builtin_nontemporal_store(u.q[1], dst + 1);
        }
    }
}

// ---------------- attn GEMM partials: Vt loads issued BEFORE E (vmcnt order), E depth 2 ----------------
__global__ __launch_bounds__(256) void attn_gemm(const unsigned short* __restrict__ E,
                                                 const unsigned short* __restrict__ Vt,
                                                 float* __restrict__ part){
    __shared__ unsigned short As[64*36];
    int tid = threadIdx.x;
    int wave = tid >> 6, lane = tid & 63;
    int kk0 = blockIdx.x*64;
    int per = (ACHUNKS + ZSPLIT - 1) / ZSPLIT;
    int c0 = blockIdx.y*per;
    int c1 = min(ACHUNKS, c0 + per);
    int l15 = lane & 15;
    int q8 = (lane >> 4) * 8;
    int d0 = wave*32;
    int n_l = tid & 31;
    int k8 = (tid >> 5) * 8;
    f32x4 acc[4][2];
    #pragma unroll
    for (int g = 0; g < 4; ++g){ acc[g][0] = (f32x4)0.f; acc[g][1] = (f32x4)0.f; }
    const unsigned short* ebase = E + (size_t)n_l*KP + kk0 + k8;
    const unsigned short* vb0p = Vt + (size_t)(d0 + l15)*NN + q8;
    const unsigned short* vb1p = vb0p + (size_t)16*NN;
    // prime: short-latency Vt first, then E (depth 2)
    sh8 vb0 = lds8(vb0p + c0*32);
    sh8 vb1 = lds8(vb1p + c0*32);
    sh8 etmp = ldnt8(ebase + (size_t)c0*32*KP);
    sh8 etn = (c0 + 1 < c1) ? ldnt8(ebase + (size_t)(c0+1)*32*KP) : (sh8)0;
    for (int ch = c0; ch < c1; ++ch){
        unsigned short tmp[8];
        *reinterpret_cast<sh8*>(tmp) = etmp;
        #pragma unroll
        for (int j = 0; j < 8; ++j) As[(k8 + j)*36 + n_l] = tmp[j];
        __syncthreads();
        // issue: Vt (L2, waited next chunk) first, then E for ch+2 (HBM, 2-chunk gap)
        sh8 vbn0 = (sh8)0, vbn1 = (sh8)0, etn2 = (sh8)0;
        if (ch + 1 < c1){
            vbn0 = lds8(vb0p + (ch+1)*32);
            vbn1 = lds8(vb1p + (ch+1)*32);
        }
        if (ch + 2 < c1){
            etn2 = ldnt8(ebase + (size_t)(ch+2)*32*KP);
        }
        #pragma unroll
        for (int g = 0; g < 4; ++g){
            const unsigned short* ap = &As[(g*16 + l15)*36 + q8];
            union { struct { ushort4 lo, hi; } u; sh8 v; } af;
            af.u.lo = *reinterpret_cast<const ushort4*>(ap);
            af.u.hi = *reinterpret_cast<const ushort4*>(ap + 4);
            acc[g][0] = __builtin_amdgcn_mfma_f32_16x16x32_bf16(af.v, vb0, acc[g][0], 0, 0, 0);
            acc[g][1] = __builtin_amdgcn_mfma_f32_16x16x32_bf16(af.v, vb1, acc[g][1], 0, 0, 0);
        }
        __syncthreads();
        etmp = etn; etn = etn2; vb0 = vbn0; vb1 = vbn1;
    }
    float* pbase = part + (size_t)blockIdx.y*KK*128;
    int rq = (lane >> 4) * 4;
    #pragma unroll
    for (int g = 0; g < 4; ++g){
        #pragma unroll
        for (int ni = 0; ni < 2; ++ni){
            int d = d0 + ni*16 + l15;
            #pragma unroll
            for (int reg = 0; reg < 4; ++reg){
                int kk = kk0 + g*16 + rq + reg;
                if (kk < KK) pbase[(size_t)kk*128 + d] = acc[g][ni][reg];
            }
        }
    }
}

// ---------------- xout GEMM: 32m x 128n, K-split x2, chunk-modulo buffers ----------------
// 8 chunks of 128 k. B double-buffered (distance 2, issued FIRST per chunk so waits leave E
// flying -- vmcnt is in-order); E quad-buffered (distance 3, issued LAST).
__global__ __launch_bounds__(256) void xout_gemm(const unsigned short* __restrict__ E,
                                                 const unsigned short* __restrict__ B,
                                                 float* __restrict__ xpart){
    int tid = threadIdx.x;
    int wave = tid >> 6, lane = tid & 63;
    int wm = wave >> 1, wn = wave & 1;
    int m_base = blockIdx.x*32 + wm*16;
    int kz = blockIdx.y*1024;
    int l15 = lane & 15;
    int roff = (lane >> 4) * 8;
    const unsigned short* ap = E + (size_t)(m_base + l15)*KP + kz + roff;
    const unsigned short* bp = B + (size_t)(wn*64 + l15)*KP + kz + roff;
    f32x4 acc[4];
    #pragma unroll
    for (int j = 0; j < 4; ++j) acc[j] = (f32x4)0.f;
    sh8 Bb[2][4][4];   // [slot][kstep][nfrag]
    sh8 Eb[4][4];      // [slot][kstep]
    // prime: B chunks 0,1 first (older in vmcnt order), then E chunks 0,1,2
    #pragma unroll
    for (int c = 0; c < 2; ++c)
        #pragma unroll
        for (int s = 0; s < 4; ++s)
            #pragma unroll
            for (int j = 0; j < 4; ++j)
                Bb[c][s][j] = lds8(bp + (size_t)j*16*KP + c*128 + s*32);
    #pragma unroll
    for (int c = 0; c < 3; ++c)
        #pragma unroll
        for (int s = 0; s < 4; ++s)
            Eb[c][s] = lds8(ap + c*128 + s*32);
    #pragma unroll
    for (int c = 0; c < 8; ++c){
        #pragma unroll
        for (int s = 0; s < 4; ++s){
            sh8 e = Eb[c & 3][s];
            #pragma unroll
            for (int j = 0; j < 4; ++j)
                acc[j] = __builtin_amdgcn_mfma_f32_16x16x32_bf16(e, Bb[c & 1][s][j], acc[j], 0, 0, 0);
        }
        if (c + 2 < 8){
            #pragma unroll
            for (int s = 0; s < 4; ++s)
                #pragma unroll
                for (int j = 0; j < 4; ++j)
                    Bb[c & 1][s][j] = lds8(bp + (size_t)j*16*KP + (c+2)*128 + s*32);
        }
        if (c + 3 < 8){
            #pragma unroll
            for (int s = 0; s < 4; ++s)
                Eb[(c+3) & 3][s] = lds8(ap + (c+3)*128 + s*32);
        }
    }
    float* pbase = xpart + (size_t)blockIdx.y*NN*128;
    int rq = (lane >> 4) * 4;
    #pragma unroll
    for (int ni = 0; ni < 4; ++ni){
        int gn = wn*64 + ni*16 + l15;
        #pragma unroll
        for (int reg = 0; reg < 4; ++reg){
            int gm = m_base + rq + reg;
            if (gm < NN) pbase[(size_t)gm*128 + gn] = acc[ni][reg];
        }
    }
}

// ---------------- xout reduce: ybuf = bf16(zdinv[n] * (p0 + p1)) ----------------
__global__ __launch_bounds__(256) void xred(const float* __restrict__ xp, const float* __restrict__ zdinv,
                                            unsigned short* __restrict__ out){
    int i = blockIdx.x*256 + threadIdx.x;
    if (i < NN*32){
        int row = i >> 5;
        float4 p0 = ld4(xp + (size_t)i*4);
        float4 p1 = ld4(xp + (size_t)NN*128 + (size_t)i*4);
        float sc = zdinv[row];
        ushort4 o;
        o.x = f2bf((p0.x + p1.x)*sc);
        o.y = f2bf((p0.y + p1.y)*sc);
        o.z = f2bf((p0.z + p1.z)*sc);
        o.w = f2bf((p0.w + p1.w)*sc);
        *reinterpret_cast<ushort4*>(out + (size_t)i*4) = o;
    }
}

// ---------------- LayerNorm over D=128 (with partial-sum input) ----------------
__global__ __launch_bounds__(128) void ln_ker(const float* __restrict__ in, int nparts,
                                              const float* __restrict__ resid,
                                              const float* __restrict__ g, const float* __restrict__ be,
                                              float* __restrict__ out){
    __shared__ float rs[128], rq[128];
    int r = blockIdx.x, t = threadIdx.x;
    float v = 0.f;
    for (int p = 0; p < nparts; ++p) v += in[(size_t)p*KK*128 + r*128 + t];
    if (resid) v += resid[r*128 + t];
    rs[t] = v; rq[t] = v*v;
    __syncthreads();
    for (int off = 64; off > 0; off >>= 1){
        if (t < off){ rs[t] += rs[t+off]; rq[t] += rq[t+off]; }
        __syncthreads();
    }
    float mean = rs[0]*(1.f/128.f);
    float var = rq[0]*(1.f/128.f) - mean*mean;
    out[r*128 + t] = (v - mean)*rsqrtf(var + 1e-5f)*g[t] + be[t];
}

// ---------------- launcher ----------------
extern "C" void kernel_launch(void* const* d_in, const int* in_sizes, int n_in,
                              void* d_out, int out_size, void* d_ws, size_t ws_size,
                              hipStream_t stream){
    cfp x  = (cfp)d_in[0];
    const int* ei = (const int*)d_in[1];
    const int* esrc = ei;
    const int* edst = ei + EE;
    cfp W1=(cfp)d_in[3], b1=(cfp)d_in[4], W2=(cfp)d_in[5], b2=(cfp)d_in[6];
    cfp S =(cfp)d_in[7];
    cfp Wq=(cfp)d_in[8],  bq=(cfp)d_in[9],  Wk=(cfp)d_in[10], bk=(cfp)d_in[11];
    cfp Wv=(cfp)d_in[12], bv=(cfp)d_in[13], Wo=(cfp)d_in[14], bo=(cfp)d_in[15];
    cfp g0=(cfp)d_in[16], be0=(cfp)d_in[17], g1=(cfp)d_in[18], be1=(cfp)d_in[19];
    cfp Wl=(cfp)d_in[20], bl=(cfp)d_in[21], W3=(cfp)d_in[22], b3=(cfp)d_in[23];
    cfp W4=(cfp)d_in[24], b4=(cfp)d_in[25], W5=(cfp)d_in[26], b5=(cfp)d_in[27];

    char* wsb = (char*)d_ws;
    const size_t MB = 1048576;
    int*   deg    = (int*)  (wsb + 0);
    float* dinv   = (float*)(wsb + 81920);
    int*   rows   = (int*)  (wsb + 163840);
    int*   cursor = (int*)  (wsb + 245760);
    int*   col    = (int*)  (wsb + 327680);          // ends at 1607680
    float* zeros  = (float*)(wsb + 1703936);         // 512B-aligned zero bias
    float* Qb     = (float*)(wsb + 2*MB);
    float* o1     = (float*)(wsb + 3*MB);    // also xl3 (fp32)
    float* o2     = (float*)(wsb + 4*MB);
    float* o3     = (float*)(wsb + 5*MB);
    float* xlb    = (float*)(wsb + 6*MB);
    float* zpart  = (float*)(wsb + 7*MB);                 // 16 x NN fp32
    float* zinv   = (float*)(wsb + 10*MB);
    float* zdinv  = (float*)(wsb + 10*MB + 131072);
    unsigned short* Wts  = (unsigned short*)(wsb + 10*MB + 262144);
    unsigned short* Qbf  = (unsigned short*)(wsb + 11*MB);
    unsigned short* xlt3 = (unsigned short*)(wsb + 11*MB + 524288);  // [128 x KP] bf16
    unsigned short* xbf = (unsigned short*)(wsb + 12*MB); // also h3
    unsigned short* h1  = (unsigned short*)(wsb + 17*MB); // also g2, h4
    unsigned short* h2s = (unsigned short*)(wsb + 22*MB);
    unsigned short* ybuf= (unsigned short*)(wsb + 27*MB);
    unsigned short* Kbf = (unsigned short*)(wsb + 32*MB);
    unsigned short* Vtz = (unsigned short*)(wsb + 37*MB);
    // time-aliased region 42..62 MiB: NB3 (Vd fp32) -> part (16 MiB) -> xpart (19.6 MiB)
    float* NB3    = (float*)(wsb + 42*MB);
    float* part   = (float*)(wsb + 42*MB);
    float* xpart  = (float*)(wsb + 42*MB);
    unsigned short* E = (unsigned short*)(wsb + 62*MB);   // [NN x KP] bf16 = 78.1 MiB
    float* outp   = (float*)d_out;
    unsigned short* g2 = h1;    // h1 dead after GCN2 tgemm
    unsigned short* h3 = xbf;
    unsigned short* h4 = h1;

    (void)hipMemsetAsync(deg, 0, NN*sizeof(int), stream);
    (void)hipMemsetAsync(cursor, 0, NN*sizeof(int), stream);
    (void)hipMemsetAsync(zeros, 0, 512, stream);
    (void)hipMemsetAsync(xlt3, 0, 128*KP*sizeof(unsigned short), stream);  // pad cols must be finite

    // CSR build
    k_count<<<1250, 256, 0, stream>>>(edst, deg);
    k_scan<<<1, 1024, 0, stream>>>(deg, rows, dinv);
    k_fill<<<1250, 256, 0, stream>>>(esrc, edst, rows, cursor, col);

    // weights -> bf16 transposed; x -> bf16
    conv_wT<<<dim3(2,2,7), 256, 0, stream>>>(W1, W2, Wk, Wv, W3, W4, W5, Wts);
    conv_bf16<<<2500, 256, 0, stream>>>(x, xbf, NN*32);
    unsigned short* W1t = Wts;
    unsigned short* W2t = Wts + 16384;
    unsigned short* Wkt = Wts + 2*16384;
    unsigned short* Wvt = Wts + 3*16384;
    unsigned short* W4t = Wts + 5*16384;
    unsigned short* W5t = Wts + 6*16384;

    const int GN = 313;   // ceil(NN/64)
    const int GT = 625;   // NN/32
    const int GK = 32;    // ceil(KK/64) == KP/64

    // GCN1
    tgemm<<<GT, 256, 0, stream>>>(xbf, NN, W1t, dinv, nullptr, h1, 0);           // pre-scaled rows
    gcn_agg_bf<<<5000, 256, 0, stream>>>(h1, dinv, rows, col, b1, ybuf, 1, 0, 0);
    // GCN2 -> h2s = relu(.)·dinv (fold for shared K/V aggregation)
    tgemm<<<GT, 256, 0, stream>>>(ybuf, NN, W2t, dinv, nullptr, h1, 0);
    gcn_agg_bf<<<5000, 256, 0, stream>>>(h1, dinv, rows, col, b2, h2s, 1, 0, 1);
    // g2 = dinv·(h2s + sum h2s[src])  (single aggregation shared by K and V)
    gcn_agg_bf<<<5000, 256, 0, stream>>>(h2s, dinv, rows, col, zeros, g2, 0, 0, 0);
    // Kd = g2@Wk + bk (bf16)
    tgemm<<<GT, 256, 0, stream>>>(g2, NN, Wkt, nullptr, bk, Kbf, 0);
    // Q = S@Wq + bq (fp32) -> Qb + Qbf fused
    gemm128<<<GK, 512, 0, stream>>>(S, Wq, Qb, KK, bq, nullptr, 0, Qbf);
    // E = exp(SCALE * Kd Q^T), z partials
    s_gemm_exp<<<dim3(GN, 16), 256, 0, stream>>>(Kbf, Qbf, E, zpart);
    k_rcp32<<<79, 256, 0, stream>>>(zpart, dinv, zinv, zdinv);
    // Vd = g2@Wv + bv (fp32) -> Vtz (transposed bf16, pre-scaled by zinv[n])
    tgemm<<<GT, 256, 0, stream>>>(g2, NN, Wvt, nullptr, bv, NB3, 1);
    conv_bf16_T<<<dim3(GN, 2), 256, 0, stream>>>(NB3, Vtz, NN, NN, zinv);
    // attn partials (NB3 dead now; part aliases it)
    attn_gemm<<<dim3(GK, ZSPLIT), 256, 0, stream>>>(E, Vtz, part);
    // out = LN(sum(part) + Q)
    ln_ker<<<KK, 128, 0, stream>>>(part, ZSPLIT, Qb, g0, be0, o1);
    // o2 = o1 + relu(o1@Wo + bo)
    gemm128<<<GK, 512, 0, stream>>>(o1, Wo, o2, KK, bo, o1, 1, nullptr);
    ln_ker<<<KK, 128, 0, stream>>>(o2, 1, nullptr, g1, be1, o3);
    // xl = o3@Wl + bl ; xl3 = xl @ W3  (GCN3 weight folded into the seed side)
    gemm128<<<GK, 512, 0, stream>>>(o3, Wl, xlb, KK, bl, nullptr, 0, nullptr);
    gemm128<<<GK, 512, 0, stream>>>(xlb, W3, o1, KK, nullptr, nullptr, 0, nullptr);
    conv_bf16_T<<<dim3(GK, 2), 256, 0, stream>>>(o1, xlt3, KK, KP, nullptr);
    // ybuf[n] = bf16(zinv*dinv*(E[n] @ xl3))  == GCN3 pre-agg activations
    xout_gemm<<<dim3(GT, 2), 256, 0, stream>>>(E, xlt3, xpart);
    xred<<<2500, 256, 0, stream>>>(xpart, zdinv, ybuf);
    // GCN3 aggregation
    gcn_agg_bf<<<5000, 256, 0, stream>>>(ybuf, dinv, rows, col, b3, h3, 1, 0, 0);
    // GCN4
    tgemm<<<GT, 256, 0, stream>>>(h3, NN, W4t, dinv, nullptr, ybuf, 0);
    gcn_agg_bf<<<5000, 256, 0, stream>>>(ybuf, dinv, rows, col, b4, h4, 1, 0, 0);
    // GCN5 -> d_out (fp32)
    tgemm<<<GT, 256, 0, stream>>>(h4, NN, W5t, dinv, nullptr, ybuf, 0);
    gcn_agg_bf<<<5000, 256, 0, stream>>>(ybuf, dinv, rows, col, b5, outp, 0, 1, 0);
}